// Round 4
// baseline (543.573 us; speedup 1.0000x reference)
//
#include <hip/hip_runtime.h>
#include <stdint.h>

typedef unsigned short u16;
typedef unsigned long long u64;
typedef __attribute__((ext_vector_type(8))) short bf16x8;
typedef __attribute__((ext_vector_type(4))) float f32x4;
typedef __attribute__((ext_vector_type(16))) float f32x16;

#define KLOG2E 0.18033688011112043f  // SCALE(0.125) * log2(e)

__device__ __forceinline__ u16 f2bf(float f) {
  union { float f; unsigned u; } v; v.f = f;
  unsigned r = v.u + 0x7fffu + ((v.u >> 16) & 1u);
  return (u16)(r >> 16);
}
__device__ __forceinline__ float bf2f(u16 u) {
  union { unsigned u; float f; } v; v.u = ((unsigned)u) << 16;
  return v.f;
}

__device__ __forceinline__ void gload16(const void* g, void* l) {
  __builtin_amdgcn_global_load_lds(
      (const __attribute__((address_space(1))) unsigned int*)g,
      (__attribute__((address_space(3))) unsigned int*)l, 16, 0, 0);
}

__global__ void cvt_f32_bf16(const float4* __restrict__ s, uint2* __restrict__ d, int n4) {
  int i = blockIdx.x * blockDim.x + threadIdx.x;
  int stride = gridDim.x * blockDim.x;
  for (; i < n4; i += stride) {
    float4 v = s[i];
    uint2 o;
    o.x = (unsigned)f2bf(v.x) | ((unsigned)f2bf(v.y) << 16);
    o.y = (unsigned)f2bf(v.z) | ((unsigned)f2bf(v.w) << 16);
    d[i] = o;
  }
}

// C = A @ B^T, A [M,768] bf16, B [N,768] bf16, 128x128 tile, 4 waves.
template <int MODE>
__global__ __launch_bounds__(256, 2) void gemm_bt(
    const u16* __restrict__ A, const u16* __restrict__ Bm,
    void* __restrict__ Cp, void* __restrict__ Cp2,
    const float* __restrict__ bias, int ldc) {
  __shared__ u16 Ab[128 * 32];
  __shared__ u16 Bb[128 * 32];
  const int tid = threadIdx.x;
  const int l = tid & 63, w = tid >> 6;
  const int g = l >> 4, l15 = l & 15;
  const int wr = w >> 1, wc = w & 1;
  const int rowbase = blockIdx.y * 128, colbase = blockIdx.x * 128;

  f32x4 acc[4][4] = {};
  const char* Abase = (const char*)A + (size_t)rowbase * 1536;
  const char* Bbase = (const char*)Bm + (size_t)colbase * 1536;

  for (int kk = 0; kk < 768; kk += 32) {
    __syncthreads();
#pragma unroll
    for (int p = 0; p < 2; ++p) {
      int o = p * 4096 + w * 1024 + l * 16;
      int row = o >> 6, cb = o & 63;
      gload16(Abase + (size_t)row * 1536 + kk * 2 + cb, &Ab[(p * 4096 + w * 1024) / 2]);
      gload16(Bbase + (size_t)row * 1536 + kk * 2 + cb, &Bb[(p * 4096 + w * 1024) / 2]);
    }
    __syncthreads();
    bf16x8 af[4], bfr[4];
#pragma unroll
    for (int i = 0; i < 4; ++i) {
      af[i] = *(const bf16x8*)&Ab[(wr * 64 + i * 16 + l15) * 32 + g * 8];
      bfr[i] = *(const bf16x8*)&Bb[(wc * 64 + i * 16 + l15) * 32 + g * 8];
    }
#pragma unroll
    for (int mi = 0; mi < 4; ++mi)
#pragma unroll
      for (int ni = 0; ni < 4; ++ni)
        acc[mi][ni] = __builtin_amdgcn_mfma_f32_16x16x32_bf16(af[mi], bfr[ni], acc[mi][ni], 0, 0, 0);
  }

#pragma unroll
  for (int mi = 0; mi < 4; ++mi)
#pragma unroll
    for (int ni = 0; ni < 4; ++ni)
#pragma unroll
      for (int r = 0; r < 4; ++r) {
        int row = rowbase + wr * 64 + mi * 16 + g * 4 + r;
        int col = colbase + wc * 64 + ni * 16 + l15;
        float v = acc[mi][ni][r];
        if (MODE == 0) {
          ((u16*)Cp)[(size_t)row * ldc + col] = f2bf(v);
        } else if (MODE == 2) {
          ((float*)Cp)[(size_t)row * ldc + col] = v + bias[col];
        } else {
          int b = col >> 10, nn = col & 1023;
          if (row < 768) {
            ((u16*)Cp)[(size_t)b * 786432 + (size_t)row * 1024 + nn] = f2bf(v + bias[row]);
          } else if (row < 780) {
            ((float*)Cp2)[(size_t)b * 12288 + (size_t)(row - 768) * 1024 + nn] = v * KLOG2E;
          }
        }
      }
}

// Flash attention v4: 32x32x16 MFMA, 32 q-cols per wave, d-split wave pairs.
// grid = (b=8, h=12, qt=16), 256 threads = 4 waves.
// wave w: p = w&1 (q-group: q p*32..p*32+31), e = w>>1 (d-half: dims e*384..+383;
// finalizes k-quarter e*16..e*16+15 of each 32-k tile).
__global__ __launch_bounds__(256, 2) void attn3(
    const u16* __restrict__ QK,   // [B*N][1536] bf16 (cols 0-767 q_shared, 768-1535 k)
    const u16* __restrict__ vT,   // [B][768][1024] bf16
    const float* __restrict__ cb, // [B][12][1024], pre-scaled by KLOG2E
    const float* __restrict__ Wmix,
    u16* __restrict__ OH)         // [B*N][768] bf16
{
  __shared__ u16 Kb[2][8192];    // 2 phase-bufs x 16KB; each = 2 e-chunks x (32 rows x 256B)
  __shared__ u16 Vb[2][2048];    // 2 x 4KB: 64 d-rows x 64B (32 k bf16)
  __shared__ float Sx[4][1024];  // per-wave 4KB exchange
  __shared__ float Mx[4][32];    // per-wave 128B max/l exchange

  const int b = blockIdx.x, h = blockIdx.y, qt = blockIdx.z;
  const int tid = threadIdx.x;
  const int lane = tid & 63, w = tid >> 6;
  const int c = lane & 31, hi = lane >> 5;
  const int p = w & 1, e = w >> 1;

  const char* Qsrc = (const char*)QK + ((size_t)b * 1024 + qt * 64) * 3072;
  const char* Ksrc = (const char*)QK + (size_t)b * 1024 * 3072 + 1536;
  const char* Vsrc = (const char*)vT + (size_t)b * 1572864 + (size_t)h * 131072;
  const float* cbp = cb + (size_t)(b * 12 + h) * 1024;

  // ---- Q prologue: build qreg = B-frags of (Q .* Wmix[h] * KLOG2E), 32 q x 384 d per wave
  bf16x8 qreg[24];
#pragma unroll
  for (int dc = 0; dc < 6; ++dc) {
#pragma unroll
    for (int p4 = 0; p4 < 4; ++p4) {
      int o = p4 * 4096 + tid * 16;
      int row = o >> 8, slot = (o >> 4) & 15;
      gload16(Qsrc + (size_t)row * 3072 + dc * 256 + ((slot ^ (row & 7)) * 16),
              (char*)Kb[0] + o);
    }
    __syncthreads();
    if ((dc >= 3) == (e == 1)) {
      int row = p * 32 + c;
#pragma unroll
      for (int fd = 0; fd < 8; ++fd) {
        int slot = (fd * 2 + hi) ^ (row & 7);
        bf16x8 qv = *(const bf16x8*)&Kb[0][row * 128 + slot * 8];
        const float* wm = Wmix + h * 768 + dc * 128 + fd * 16 + hi * 8;
        float4 w0 = *(const float4*)wm;
        float4 w1 = *(const float4*)(wm + 4);
        bf16x8 qh;
        qh[0] = (short)f2bf(bf2f((u16)qv[0]) * (w0.x * KLOG2E));
        qh[1] = (short)f2bf(bf2f((u16)qv[1]) * (w0.y * KLOG2E));
        qh[2] = (short)f2bf(bf2f((u16)qv[2]) * (w0.z * KLOG2E));
        qh[3] = (short)f2bf(bf2f((u16)qv[3]) * (w0.w * KLOG2E));
        qh[4] = (short)f2bf(bf2f((u16)qv[4]) * (w1.x * KLOG2E));
        qh[5] = (short)f2bf(bf2f((u16)qv[5]) * (w1.y * KLOG2E));
        qh[6] = (short)f2bf(bf2f((u16)qv[6]) * (w1.z * KLOG2E));
        qh[7] = (short)f2bf(bf2f((u16)qv[7]) * (w1.w * KLOG2E));
        qreg[(dc % 3) * 8 + fd] = qh;
      }
    }
    __syncthreads();
  }

  auto STK = [&](int kt, int j, int buf) {
#pragma unroll
    for (int p4 = 0; p4 < 4; ++p4) {
      int o = p4 * 4096 + tid * 16;
      int ec = o >> 13, o2 = o & 8191;
      int row = o2 >> 8, slot = (o2 >> 4) & 15;
      gload16(Ksrc + (size_t)(kt * 32 + row) * 3072 + (ec * 768 + j * 256) +
                  ((slot ^ (row & 7)) * 16),
              (char*)Kb[buf] + o);
    }
  };
  auto STV = [&](int kt, int buf) {
    int o = tid * 16;
    int row = o >> 6, slot = (o >> 4) & 3;
    gload16(Vsrc + (size_t)row * 2048 + kt * 64 + ((slot ^ ((row >> 1) & 3)) * 16),
            (char*)Vb[buf] + o);
  };

  float m_run = -1e30f, lpart = 0.f;
  f32x16 oacc0 = {}, oacc1 = {};

  STK(0, 0, 0);
  STV(0, 0);
  __syncthreads();
  int ph = 0, vph = 0;

  for (int kt = 0; kt < 32; ++kt) {
    f32x16 sp = {};
#pragma unroll
    for (int j = 0; j < 3; ++j) {
      if (j < 2) STK(kt, j + 1, ph ^ 1);
      else if (kt < 31) STK(kt + 1, 0, ph ^ 1);
      if (j == 1 && kt < 31) STV(kt + 1, vph ^ 1);
#pragma unroll
      for (int ds = 0; ds < 8; ++ds) {
        int slot = (ds * 2 + hi) ^ (c & 7);
        bf16x8 a = *(const bf16x8*)&Kb[ph][e * 4096 + c * 128 + slot * 8];
        sp = __builtin_amdgcn_mfma_f32_32x32x16_bf16(a, qreg[j * 8 + ds], sp, 0, 0, 0);
      }
      __syncthreads();
      ph ^= 1;
    }

    // ---- d-split exchange: send the non-finalized 8 regs, add partner's partials
    float4 s0, s1;
    if (e == 0) {
      s0.x = sp[8];  s0.y = sp[9];  s0.z = sp[10]; s0.w = sp[11];
      s1.x = sp[12]; s1.y = sp[13]; s1.z = sp[14]; s1.w = sp[15];
    } else {
      s0.x = sp[0]; s0.y = sp[1]; s0.z = sp[2]; s0.w = sp[3];
      s1.x = sp[4]; s1.y = sp[5]; s1.z = sp[6]; s1.w = sp[7];
    }
    *(float4*)&Sx[w][lane * 4] = s0;
    *(float4*)&Sx[w][(64 + lane) * 4] = s1;
    __syncthreads();
    float4 r0 = *(const float4*)&Sx[w ^ 2][lane * 4];
    float4 r1 = *(const float4*)&Sx[w ^ 2][(64 + lane) * 4];
    float fv[8];
    if (e == 0) {
      fv[0] = sp[0] + r0.x; fv[1] = sp[1] + r0.y; fv[2] = sp[2] + r0.z; fv[3] = sp[3] + r0.w;
      fv[4] = sp[4] + r1.x; fv[5] = sp[5] + r1.y; fv[6] = sp[6] + r1.z; fv[7] = sp[7] + r1.w;
    } else {
      fv[0] = sp[8] + r0.x;  fv[1] = sp[9] + r0.y;  fv[2] = sp[10] + r0.z; fv[3] = sp[11] + r0.w;
      fv[4] = sp[12] + r1.x; fv[5] = sp[13] + r1.y; fv[6] = sp[14] + r1.z; fv[7] = sp[15] + r1.w;
    }
    // content bias (k-row indexed); rows = kt*32 + e*16 + 4*hi + {0..3} and +8+{0..3}
    {
      const float* cbb = cbp + kt * 32 + e * 16 + 4 * hi;
      float4 c0 = *(const float4*)cbb;
      float4 c1 = *(const float4*)(cbb + 8);
      fv[0] += c0.x; fv[1] += c0.y; fv[2] += c0.z; fv[3] += c0.w;
      fv[4] += c1.x; fv[5] += c1.y; fv[6] += c1.z; fv[7] += c1.w;
    }

    // ---- online softmax (per-lane col q; k spread over regs + hi + partner)
    float mloc = fmaxf(fmaxf(fmaxf(fv[0], fv[1]), fmaxf(fv[2], fv[3])),
                       fmaxf(fmaxf(fv[4], fv[5]), fmaxf(fv[6], fv[7])));
    mloc = fmaxf(mloc, __shfl_xor(mloc, 32));
    Mx[w][c] = mloc;
    __syncthreads();
    float pm = fmaxf(mloc, Mx[w ^ 2][c]);
    if (__ballot(pm > m_run)) {
      float mnew = fmaxf(m_run, pm);
      float alpha = exp2f(m_run - mnew);
      lpart *= alpha;
      oacc0 *= alpha;
      oacc1 *= alpha;
      m_run = mnew;
    }
    float pv[8];
    float rs = 0.f;
#pragma unroll
    for (int r = 0; r < 8; ++r) {
      pv[r] = exp2f(fv[r] - m_run);
      rs += pv[r];
    }
    rs += __shfl_xor(rs, 32);
    lpart += rs;

    // ---- pack P to PV B-frag in-register (cvt_pk + permlane32_swap)
    // Packs: xw=k{4hi+0,4hi+1}, yw=k{4hi+2,4hi+3}, zw=k{8+4hi+0,8+4hi+1}, tw=k{8+4hi+2,+3}
    // swap(xw,zw): xw.hi<-zw.lo (k{8,9}), zw.lo<-xw.hi (k{4,5}) => xw=u0, zw=u2.
    unsigned xw, yw, zw, tw;
    asm("v_cvt_pk_bf16_f32 %0, %1, %2" : "=v"(xw) : "v"(pv[0]), "v"(pv[1]));
    asm("v_cvt_pk_bf16_f32 %0, %1, %2" : "=v"(yw) : "v"(pv[2]), "v"(pv[3]));
    asm("v_cvt_pk_bf16_f32 %0, %1, %2" : "=v"(zw) : "v"(pv[4]), "v"(pv[5]));
    asm("v_cvt_pk_bf16_f32 %0, %1, %2" : "=v"(tw) : "v"(pv[6]), "v"(pv[7]));
    asm volatile("v_permlane32_swap_b32 %0, %1" : "+v"(xw), "+v"(zw));
    asm volatile("v_permlane32_swap_b32 %0, %1" : "+v"(yw), "+v"(tw));
    union { unsigned u[4]; bf16x8 v; } bfr;
    bfr.u[0] = xw; bfr.u[1] = yw; bfr.u[2] = zw; bfr.u[3] = tw;

    // ---- PV: A = vT tile rows (32 d x 16 k) from LDS, k-quarter e
    {
      int row0 = c;
      int sl0 = (e * 2 + hi) ^ ((row0 >> 1) & 3);
      bf16x8 a0 = *(const bf16x8*)&Vb[vph][row0 * 32 + sl0 * 8];
      oacc0 = __builtin_amdgcn_mfma_f32_32x32x16_bf16(a0, bfr.v, oacc0, 0, 0, 0);
      int row1 = 32 + c;
      int sl1 = (e * 2 + hi) ^ ((row1 >> 1) & 3);
      bf16x8 a1 = *(const bf16x8*)&Vb[vph][row1 * 32 + sl1 * 8];
      oacc1 = __builtin_amdgcn_mfma_f32_32x32x16_bf16(a1, bfr.v, oacc1, 0, 0, 0);
    }
    vph ^= 1;
  }

  // ---- epilogue: combine k-quarter partial O across the pair, divide by l, store
  __syncthreads();
  {
    float4 o0, o1, o2, o3;
    if (e == 0) {  // send oacc1 (d 32-63), keep oacc0
      o0.x = oacc1[0];  o0.y = oacc1[1];  o0.z = oacc1[2];  o0.w = oacc1[3];
      o1.x = oacc1[4];  o1.y = oacc1[5];  o1.z = oacc1[6];  o1.w = oacc1[7];
      o2.x = oacc1[8];  o2.y = oacc1[9];  o2.z = oacc1[10]; o2.w = oacc1[11];
      o3.x = oacc1[12]; o3.y = oacc1[13]; o3.z = oacc1[14]; o3.w = oacc1[15];
    } else {
      o0.x = oacc0[0];  o0.y = oacc0[1];  o0.z = oacc0[2];  o0.w = oacc0[3];
      o1.x = oacc0[4];  o1.y = oacc0[5];  o1.z = oacc0[6];  o1.w = oacc0[7];
      o2.x = oacc0[8];  o2.y = oacc0[9];  o2.z = oacc0[10]; o2.w = oacc0[11];
      o3.x = oacc0[12]; o3.y = oacc0[13]; o3.z = oacc0[14]; o3.w = oacc0[15];
    }
    *(float4*)&Sx[w][lane * 4] = o0;
    *(float4*)&Sx[w][(64 + lane) * 4] = o1;
    *(float4*)&Sx[w][(128 + lane) * 4] = o2;
    *(float4*)&Sx[w][(192 + lane) * 4] = o3;
    Mx[w][c] = lpart;
    __syncthreads();
    float4 q0 = *(const float4*)&Sx[w ^ 2][lane * 4];
    float4 q1 = *(const float4*)&Sx[w ^ 2][(64 + lane) * 4];
    float4 q2 = *(const float4*)&Sx[w ^ 2][(128 + lane) * 4];
    float4 q3 = *(const float4*)&Sx[w ^ 2][(192 + lane) * 4];
    float lfull = lpart + Mx[w ^ 2][c];
    float rdiv = 1.f / lfull;
    float od[16];
    if (e == 0) {
      od[0] = oacc0[0] + q0.x;   od[1] = oacc0[1] + q0.y;   od[2] = oacc0[2] + q0.z;   od[3] = oacc0[3] + q0.w;
      od[4] = oacc0[4] + q1.x;   od[5] = oacc0[5] + q1.y;   od[6] = oacc0[6] + q1.z;   od[7] = oacc0[7] + q1.w;
      od[8] = oacc0[8] + q2.x;   od[9] = oacc0[9] + q2.y;   od[10] = oacc0[10] + q2.z; od[11] = oacc0[11] + q2.w;
      od[12] = oacc0[12] + q3.x; od[13] = oacc0[13] + q3.y; od[14] = oacc0[14] + q3.z; od[15] = oacc0[15] + q3.w;
    } else {
      od[0] = oacc1[0] + q0.x;   od[1] = oacc1[1] + q0.y;   od[2] = oacc1[2] + q0.z;   od[3] = oacc1[3] + q0.w;
      od[4] = oacc1[4] + q1.x;   od[5] = oacc1[5] + q1.y;   od[6] = oacc1[6] + q1.z;   od[7] = oacc1[7] + q1.w;
      od[8] = oacc1[8] + q2.x;   od[9] = oacc1[9] + q2.y;   od[10] = oacc1[10] + q2.z; od[11] = oacc1[11] + q2.w;
      od[12] = oacc1[12] + q3.x; od[13] = oacc1[13] + q3.y; od[14] = oacc1[14] + q3.z; od[15] = oacc1[15] + q3.w;
    }
    int n = qt * 64 + p * 32 + c;
#pragma unroll
    for (int a = 0; a < 4; ++a) {
      u64 pk = (u64)f2bf(od[a * 4 + 0] * rdiv) |
               ((u64)f2bf(od[a * 4 + 1] * rdiv) << 16) |
               ((u64)f2bf(od[a * 4 + 2] * rdiv) << 32) |
               ((u64)f2bf(od[a * 4 + 3] * rdiv) << 48);
      *(u64*)&OH[((size_t)b * 1024 + n) * 768 + h * 64 + e * 32 + a * 8 + 4 * hi] = pk;
    }
  }
}

static inline int cvtblocks(int n4) {
  int nb = (n4 + 255) / 256;
  return nb > 2048 ? 2048 : nb;
}

extern "C" void kernel_launch(void* const* d_in, const int* in_sizes, int n_in,
                              void* d_out, int out_size, void* d_ws, size_t ws_size,
                              hipStream_t stream) {
  (void)in_sizes; (void)n_in; (void)out_size; (void)ws_size;
  const float* x = (const float*)d_in[0];
  const float* Wq = (const float*)d_in[1];
  const float* Wk = (const float*)d_in[2];
  const float* Wv = (const float*)d_in[3];
  const float* bv = (const float*)d_in[4];
  const float* Wmix = (const float*)d_in[5];
  const float* Wcb = (const float*)d_in[6];
  const float* Wproj = (const float*)d_in[7];
  const float* bproj = (const float*)d_in[8];
  float* out = (float*)d_out;

  char* ws = (char*)d_ws;
  u16* xbf = (u16*)(ws);                 // 12582912 B
  u16* Wqk = (u16*)(ws + 12582912);      // 2359296 B
  u16* Wvcb = (u16*)(ws + 14942208);     // 1376256 B
  u16* Wpj = (u16*)(ws + 16318464);      // 1179648 B
  u16* QKb = (u16*)(ws + 17498112);      // 25165824 B
  u16* vT = (u16*)(ws + 42663936);       // 12582912 B
  float* cbb = (float*)(ws + 55246848);  // 393216 B
  u16* OH = (u16*)(ws + 55640064);       // 12582912 B

  cvt_f32_bf16<<<cvtblocks(1572864), 256, 0, stream>>>((const float4*)x, (uint2*)xbf, 1572864);
  cvt_f32_bf16<<<cvtblocks(147456), 256, 0, stream>>>((const float4*)Wq, (uint2*)Wqk, 147456);
  cvt_f32_bf16<<<cvtblocks(147456), 256, 0, stream>>>((const float4*)Wk, (uint2*)(Wqk + 589824), 147456);
  cvt_f32_bf16<<<cvtblocks(147456), 256, 0, stream>>>((const float4*)Wv, (uint2*)Wvcb, 147456);
  cvt_f32_bf16<<<cvtblocks(2304), 256, 0, stream>>>((const float4*)Wcb, (uint2*)(Wvcb + 589824), 2304);
  cvt_f32_bf16<<<cvtblocks(147456), 256, 0, stream>>>((const float4*)Wproj, (uint2*)Wpj, 147456);

  gemm_bt<0><<<dim3(12, 64), 256, 0, stream>>>(xbf, Wqk, QKb, nullptr, nullptr, 1536);
  gemm_bt<1><<<dim3(64, 7), 256, 0, stream>>>(Wvcb, xbf, vT, cbb, bv, 0);
  attn3<<<dim3(8, 12, 16), 256, 0, stream>>>(QKb, vT, cbb, Wmix, OH);
  gemm_bt<2><<<dim3(6, 64), 256, 0, stream>>>(OH, Wpj, out, nullptr, bproj, 768);
}

// Round 5
// 408.316 us; speedup vs baseline: 1.3313x; 1.3313x over previous
//
#include <hip/hip_runtime.h>
#include <stdint.h>

typedef unsigned short u16;
typedef unsigned long long u64;
typedef __attribute__((ext_vector_type(8))) short bf16x8;
typedef __attribute__((ext_vector_type(4))) float f32x4;
typedef __attribute__((ext_vector_type(16))) float f32x16;

#define KLOG2E 0.18033688011112043f  // SCALE(0.125) * log2(e)
#define EXP2F(x) __builtin_amdgcn_exp2f(x)

__device__ __forceinline__ u16 f2bf(float f) {
  union { float f; unsigned u; } v; v.f = f;
  unsigned r = v.u + 0x7fffu + ((v.u >> 16) & 1u);
  return (u16)(r >> 16);
}
__device__ __forceinline__ float bf2f(u16 u) {
  union { unsigned u; float f; } v; v.u = ((unsigned)u) << 16;
  return v.f;
}

__device__ __forceinline__ void gload16(const void* g, void* l) {
  __builtin_amdgcn_global_load_lds(
      (const __attribute__((address_space(1))) unsigned int*)g,
      (__attribute__((address_space(3))) unsigned int*)l, 16, 0, 0);
}

__global__ void cvt_f32_bf16(const float4* __restrict__ s, uint2* __restrict__ d, int n4) {
  int i = blockIdx.x * blockDim.x + threadIdx.x;
  int stride = gridDim.x * blockDim.x;
  for (; i < n4; i += stride) {
    float4 v = s[i];
    uint2 o;
    o.x = (unsigned)f2bf(v.x) | ((unsigned)f2bf(v.y) << 16);
    o.y = (unsigned)f2bf(v.z) | ((unsigned)f2bf(v.w) << 16);
    d[i] = o;
  }
}

// C = A @ B^T, A [M,768] bf16, B [N,768] bf16, 128x128 tile, 4 waves.
template <int MODE>
__global__ __launch_bounds__(256, 2) void gemm_bt(
    const u16* __restrict__ A, const u16* __restrict__ Bm,
    void* __restrict__ Cp, void* __restrict__ Cp2,
    const float* __restrict__ bias, int ldc) {
  __shared__ u16 Ab[128 * 32];
  __shared__ u16 Bb[128 * 32];
  const int tid = threadIdx.x;
  const int l = tid & 63, w = tid >> 6;
  const int g = l >> 4, l15 = l & 15;
  const int wr = w >> 1, wc = w & 1;
  const int rowbase = blockIdx.y * 128, colbase = blockIdx.x * 128;

  f32x4 acc[4][4] = {};
  const char* Abase = (const char*)A + (size_t)rowbase * 1536;
  const char* Bbase = (const char*)Bm + (size_t)colbase * 1536;

  for (int kk = 0; kk < 768; kk += 32) {
    __syncthreads();
#pragma unroll
    for (int p = 0; p < 2; ++p) {
      int o = p * 4096 + w * 1024 + l * 16;
      int row = o >> 6, cb = o & 63;
      gload16(Abase + (size_t)row * 1536 + kk * 2 + cb, &Ab[(p * 4096 + w * 1024) / 2]);
      gload16(Bbase + (size_t)row * 1536 + kk * 2 + cb, &Bb[(p * 4096 + w * 1024) / 2]);
    }
    __syncthreads();
    bf16x8 af[4], bfr[4];
#pragma unroll
    for (int i = 0; i < 4; ++i) {
      af[i] = *(const bf16x8*)&Ab[(wr * 64 + i * 16 + l15) * 32 + g * 8];
      bfr[i] = *(const bf16x8*)&Bb[(wc * 64 + i * 16 + l15) * 32 + g * 8];
    }
#pragma unroll
    for (int mi = 0; mi < 4; ++mi)
#pragma unroll
      for (int ni = 0; ni < 4; ++ni)
        acc[mi][ni] = __builtin_amdgcn_mfma_f32_16x16x32_bf16(af[mi], bfr[ni], acc[mi][ni], 0, 0, 0);
  }

#pragma unroll
  for (int mi = 0; mi < 4; ++mi)
#pragma unroll
    for (int ni = 0; ni < 4; ++ni)
#pragma unroll
      for (int r = 0; r < 4; ++r) {
        int row = rowbase + wr * 64 + mi * 16 + g * 4 + r;
        int col = colbase + wc * 64 + ni * 16 + l15;
        float v = acc[mi][ni][r];
        if (MODE == 0) {
          ((u16*)Cp)[(size_t)row * ldc + col] = f2bf(v);
        } else if (MODE == 2) {
          ((float*)Cp)[(size_t)row * ldc + col] = v + bias[col];
        } else {
          int b = col >> 10, nn = col & 1023;
          if (row < 768) {
            ((u16*)Cp)[(size_t)b * 786432 + (size_t)row * 1024 + nn] = f2bf(v + bias[row]);
          } else if (row < 780) {
            ((float*)Cp2)[(size_t)b * 12288 + (size_t)(row - 768) * 1024 + nn] = v * KLOG2E;
          }
        }
      }
}

// Flash attention v5: 32x32x16 MFMA, Nq=32 per wave, k=64 tiles, d-split wave
// pairs with fully-split online softmax (merge once in epilogue).
// grid = (b=8, h=12, qt=16), 256 threads = 4 waves: wave (p = q-half, e = d-half).
__global__ __launch_bounds__(256, 2) void attn5(
    const u16* __restrict__ QK,   // [B*N][1536] bf16 (cols 0-767 q_shared, 768-1535 k)
    const u16* __restrict__ vT,   // [B][768][1024] bf16
    const float* __restrict__ cb, // [B][12][1024], pre-scaled by KLOG2E
    const float* __restrict__ Wmix,
    u16* __restrict__ OH)         // [B*N][768] bf16
{
  __shared__ u16 Kb[2][8192];        // dbuf: 64 k-rows x 256B (one 128-d chunk)
  __shared__ u16 Vb[2][4096];        // dbuf: 64 d-rows x 128B (64 k)
  __shared__ float Sx[2][2][64][20]; // padded (stride 20) pair-exchange
  __shared__ float Mx[2][2][2][32];  // epilogue m/l exchange

  const int b = blockIdx.x, h = blockIdx.y, qt = blockIdx.z;
  const int tid = threadIdx.x;
  const int lane = tid & 63, w = tid >> 6;
  const int c = lane & 31, hi = lane >> 5;
  const int p = w & 1, e = w >> 1;

  const char* Qsrc = (const char*)QK + ((size_t)b * 1024 + qt * 64) * 3072;
  const char* Ksrc = (const char*)QK + (size_t)b * 1024 * 3072 + 1536;
  const char* Vsrc = (const char*)vT + (size_t)(b * 12 + h) * 131072;
  const float* cbp = cb + (size_t)(b * 12 + h) * 1024;

  // ---- Q prologue: qreg = B-frags (16d x 32q) of Q .* Wmix[h] * KLOG2E, 384 d per wave
  bf16x8 qreg[24];
#pragma unroll
  for (int dc = 0; dc < 6; ++dc) {
#pragma unroll
    for (int p4 = 0; p4 < 4; ++p4) {
      int o = p4 * 4096 + tid * 16;
      int row = o >> 8, slot = (o >> 4) & 15;
      gload16(Qsrc + (size_t)row * 3072 + dc * 256 + ((slot ^ (row & 7)) * 16),
              (char*)Kb[0] + o);
    }
    __syncthreads();
    if ((dc >= 3) == (e == 1)) {
      int row = 32 * p + c;
#pragma unroll
      for (int t = 0; t < 8; ++t) {
        int slot = (2 * t + hi) ^ (c & 7);
        bf16x8 qv = *(const bf16x8*)((const char*)Kb[0] + row * 256 + slot * 16);
        const float* wm = Wmix + h * 768 + dc * 128 + t * 16 + hi * 8;
        float4 w0 = *(const float4*)wm;
        float4 w1 = *(const float4*)(wm + 4);
        bf16x8 qh;
        qh[0] = (short)f2bf(bf2f((u16)qv[0]) * (w0.x * KLOG2E));
        qh[1] = (short)f2bf(bf2f((u16)qv[1]) * (w0.y * KLOG2E));
        qh[2] = (short)f2bf(bf2f((u16)qv[2]) * (w0.z * KLOG2E));
        qh[3] = (short)f2bf(bf2f((u16)qv[3]) * (w0.w * KLOG2E));
        qh[4] = (short)f2bf(bf2f((u16)qv[4]) * (w1.x * KLOG2E));
        qh[5] = (short)f2bf(bf2f((u16)qv[5]) * (w1.y * KLOG2E));
        qh[6] = (short)f2bf(bf2f((u16)qv[6]) * (w1.z * KLOG2E));
        qh[7] = (short)f2bf(bf2f((u16)qv[7]) * (w1.w * KLOG2E));
        qreg[(dc % 3) * 8 + t] = qh;
      }
    }
    __syncthreads();
  }

  auto STK = [&](int kt, int dc, int buf) {
#pragma unroll
    for (int p4 = 0; p4 < 4; ++p4) {
      int o = p4 * 4096 + tid * 16;
      int row = o >> 8, slot = (o >> 4) & 15;
      gload16(Ksrc + (size_t)(kt * 64 + row) * 3072 + dc * 256 + ((slot ^ (row & 7)) * 16),
              (char*)Kb[buf] + o);
    }
  };
  auto STV = [&](int kt, int buf) {
#pragma unroll
    for (int p4 = 0; p4 < 2; ++p4) {
      int o = p4 * 4096 + tid * 16;
      int row = o >> 7, slot = (o >> 4) & 7;
      gload16(Vsrc + (size_t)row * 2048 + kt * 128 + ((slot ^ (row & 7)) * 16),
              (char*)Vb[buf] + o);
    }
  };

  float m_run = -1e30f, lpart = 0.f;
  f32x16 oacc0 = {}, oacc1 = {};
  STK(0, 0, 0);
  STV(0, 0);
  __syncthreads();
  int kb = 0, vph = 0;

  for (int kt = 0; kt < 16; ++kt) {
    f32x16 s0 = {}, s1 = {};
    // ---- QK phases: chunk order interleaves halves so both pairs work alternately
#pragma unroll
    for (int j = 0; j < 6; ++j) {
      constexpr int SIGA[6] = {0, 3, 1, 4, 2, 5};
      const int dcur = SIGA[j];
      if (j < 5) STK(kt, SIGA[j + 1], kb ^ 1);
      else if (kt < 15) STK(kt + 1, 0, kb ^ 1);
      if (j == 1 && kt < 15) STV(kt + 1, vph ^ 1);
      if (e == 0) {
        if (dcur < 3) {
#pragma unroll
          for (int t = 0; t < 8; ++t) {
            int slot = (2 * t + hi) ^ (c & 7);
            bf16x8 a0 = *(const bf16x8*)((const char*)Kb[kb] + c * 256 + slot * 16);
            bf16x8 a1 = *(const bf16x8*)((const char*)Kb[kb] + (32 + c) * 256 + slot * 16);
            s0 = __builtin_amdgcn_mfma_f32_32x32x16_bf16(a0, qreg[dcur * 8 + t], s0, 0, 0, 0);
            s1 = __builtin_amdgcn_mfma_f32_32x32x16_bf16(a1, qreg[dcur * 8 + t], s1, 0, 0, 0);
          }
        }
      } else {
        if (dcur >= 3) {
#pragma unroll
          for (int t = 0; t < 8; ++t) {
            int slot = (2 * t + hi) ^ (c & 7);
            bf16x8 a0 = *(const bf16x8*)((const char*)Kb[kb] + c * 256 + slot * 16);
            bf16x8 a1 = *(const bf16x8*)((const char*)Kb[kb] + (32 + c) * 256 + slot * 16);
            s0 = __builtin_amdgcn_mfma_f32_32x32x16_bf16(a0, qreg[(dcur - 3) * 8 + t], s0, 0, 0, 0);
            s1 = __builtin_amdgcn_mfma_f32_32x32x16_bf16(a1, qreg[(dcur - 3) * 8 + t], s1, 0, 0, 0);
          }
        }
      }
      __syncthreads();
      kb ^= 1;
    }

    // ---- d-split exchange: wave e finalizes k-half e, sends the other
    {
      float* sxo = &Sx[p][e][lane][0];
      if (e == 0) {
#pragma unroll
        for (int u = 0; u < 4; ++u) {
          float4 t4;
          t4.x = s1[4 * u]; t4.y = s1[4 * u + 1]; t4.z = s1[4 * u + 2]; t4.w = s1[4 * u + 3];
          *(float4*)(sxo + 4 * u) = t4;
        }
      } else {
#pragma unroll
        for (int u = 0; u < 4; ++u) {
          float4 t4;
          t4.x = s0[4 * u]; t4.y = s0[4 * u + 1]; t4.z = s0[4 * u + 2]; t4.w = s0[4 * u + 3];
          *(float4*)(sxo + 4 * u) = t4;
        }
      }
    }
    __syncthreads();
    float fv[16];
    {
      const float* sxi = &Sx[p][e ^ 1][lane][0];
#pragma unroll
      for (int u = 0; u < 4; ++u) {
        float4 r4 = *(const float4*)(sxi + 4 * u);
        if (e == 0) {
          fv[4 * u] = s0[4 * u] + r4.x;     fv[4 * u + 1] = s0[4 * u + 1] + r4.y;
          fv[4 * u + 2] = s0[4 * u + 2] + r4.z; fv[4 * u + 3] = s0[4 * u + 3] + r4.w;
        } else {
          fv[4 * u] = s1[4 * u] + r4.x;     fv[4 * u + 1] = s1[4 * u + 1] + r4.y;
          fv[4 * u + 2] = s1[4 * u + 2] + r4.z; fv[4 * u + 3] = s1[4 * u + 3] + r4.w;
        }
      }
    }
    // content bias: k = kt*64 + 32e + 8*(r>>2) + 4hi + (r&3)
    {
      const float* cbb2 = cbp + kt * 64 + 32 * e + 4 * hi;
#pragma unroll
      for (int jj = 0; jj < 4; ++jj) {
        float4 cv = *(const float4*)(cbb2 + 8 * jj);
        fv[4 * jj] += cv.x; fv[4 * jj + 1] += cv.y;
        fv[4 * jj + 2] += cv.z; fv[4 * jj + 3] += cv.w;
      }
    }

    // ---- per-wave independent online softmax over its 32-k half
    float pmax = fv[0];
#pragma unroll
    for (int r = 1; r < 16; ++r) pmax = fmaxf(pmax, fv[r]);
    pmax = fmaxf(pmax, __shfl_xor(pmax, 32));
    if (__ballot(pmax > m_run)) {
      float mnew = fmaxf(m_run, pmax);
      float alpha = EXP2F(m_run - mnew);
      lpart *= alpha;
      oacc0 *= alpha;
      oacc1 *= alpha;
      m_run = mnew;
    }
    float pvv[16];
    float rs = 0.f;
#pragma unroll
    for (int r = 0; r < 16; ++r) {
      pvv[r] = EXP2F(fv[r] - m_run);
      rs += pvv[r];
    }
    rs += __shfl_xor(rs, 32);
    lpart += rs;

    // ---- pack P into two PV B-frags in-register (v4-verified recipe)
    bf16x8 pf0, pf1;
    {
      unsigned xw, yw, zw, tw;
      asm("v_cvt_pk_bf16_f32 %0, %1, %2" : "=v"(xw) : "v"(pvv[0]), "v"(pvv[1]));
      asm("v_cvt_pk_bf16_f32 %0, %1, %2" : "=v"(yw) : "v"(pvv[2]), "v"(pvv[3]));
      asm("v_cvt_pk_bf16_f32 %0, %1, %2" : "=v"(zw) : "v"(pvv[4]), "v"(pvv[5]));
      asm("v_cvt_pk_bf16_f32 %0, %1, %2" : "=v"(tw) : "v"(pvv[6]), "v"(pvv[7]));
      asm volatile("v_permlane32_swap_b32 %0, %1" : "+v"(xw), "+v"(zw));
      asm volatile("v_permlane32_swap_b32 %0, %1" : "+v"(yw), "+v"(tw));
      union { unsigned u[4]; bf16x8 v; } bu;
      bu.u[0] = xw; bu.u[1] = yw; bu.u[2] = zw; bu.u[3] = tw;
      pf0 = bu.v;
      asm("v_cvt_pk_bf16_f32 %0, %1, %2" : "=v"(xw) : "v"(pvv[8]), "v"(pvv[9]));
      asm("v_cvt_pk_bf16_f32 %0, %1, %2" : "=v"(yw) : "v"(pvv[10]), "v"(pvv[11]));
      asm("v_cvt_pk_bf16_f32 %0, %1, %2" : "=v"(zw) : "v"(pvv[12]), "v"(pvv[13]));
      asm("v_cvt_pk_bf16_f32 %0, %1, %2" : "=v"(tw) : "v"(pvv[14]), "v"(pvv[15]));
      asm volatile("v_permlane32_swap_b32 %0, %1" : "+v"(xw), "+v"(zw));
      asm volatile("v_permlane32_swap_b32 %0, %1" : "+v"(yw), "+v"(tw));
      union { unsigned u[4]; bf16x8 v; } bu2;
      bu2.u[0] = xw; bu2.u[1] = yw; bu2.u[2] = zw; bu2.u[3] = tw;
      pf1 = bu2.v;
    }

    // ---- PV: A = V rows (32d x 16k) from LDS at wave's k-half
    {
      int sl0 = (4 * e + hi) ^ (c & 7);
      int sl1 = (4 * e + 2 + hi) ^ (c & 7);
      bf16x8 v00 = *(const bf16x8*)((const char*)Vb[vph] + c * 128 + sl0 * 16);
      bf16x8 v10 = *(const bf16x8*)((const char*)Vb[vph] + (32 + c) * 128 + sl0 * 16);
      oacc0 = __builtin_amdgcn_mfma_f32_32x32x16_bf16(v00, pf0, oacc0, 0, 0, 0);
      oacc1 = __builtin_amdgcn_mfma_f32_32x32x16_bf16(v10, pf0, oacc1, 0, 0, 0);
      bf16x8 v01 = *(const bf16x8*)((const char*)Vb[vph] + c * 128 + sl1 * 16);
      bf16x8 v11 = *(const bf16x8*)((const char*)Vb[vph] + (32 + c) * 128 + sl1 * 16);
      oacc0 = __builtin_amdgcn_mfma_f32_32x32x16_bf16(v01, pf1, oacc0, 0, 0, 0);
      oacc1 = __builtin_amdgcn_mfma_f32_32x32x16_bf16(v11, pf1, oacc1, 0, 0, 0);
    }
    vph ^= 1;
  }

  // ---- epilogue: merge split softmax across the pair, combine O, store d-half e
  Mx[p][e][0][c] = m_run;
  Mx[p][e][1][c] = lpart;
  __syncthreads();
  float m_p = Mx[p][e ^ 1][0][c];
  float l_p = Mx[p][e ^ 1][1][c];
  float mstar = fmaxf(m_run, m_p);
  float se = EXP2F(m_run - mstar);
  float spp = EXP2F(m_p - mstar);
  float lfull = lpart * se + l_p * spp;
  {
    float* sxo = &Sx[p][e][lane][0];
    if (e == 0) {
#pragma unroll
      for (int u = 0; u < 4; ++u) {
        float4 t4;
        t4.x = oacc1[4 * u] * se;     t4.y = oacc1[4 * u + 1] * se;
        t4.z = oacc1[4 * u + 2] * se; t4.w = oacc1[4 * u + 3] * se;
        *(float4*)(sxo + 4 * u) = t4;
      }
    } else {
#pragma unroll
      for (int u = 0; u < 4; ++u) {
        float4 t4;
        t4.x = oacc0[4 * u] * se;     t4.y = oacc0[4 * u + 1] * se;
        t4.z = oacc0[4 * u + 2] * se; t4.w = oacc0[4 * u + 3] * se;
        *(float4*)(sxo + 4 * u) = t4;
      }
    }
  }
  __syncthreads();
  {
    const float* sxi = &Sx[p][e ^ 1][lane][0];
    float rdiv = 1.f / lfull;
    float od[16];
#pragma unroll
    for (int u = 0; u < 4; ++u) {
      float4 r4 = *(const float4*)(sxi + 4 * u);
      if (e == 0) {
        od[4 * u] = oacc0[4 * u] * se + r4.x;
        od[4 * u + 1] = oacc0[4 * u + 1] * se + r4.y;
        od[4 * u + 2] = oacc0[4 * u + 2] * se + r4.z;
        od[4 * u + 3] = oacc0[4 * u + 3] * se + r4.w;
      } else {
        od[4 * u] = oacc1[4 * u] * se + r4.x;
        od[4 * u + 1] = oacc1[4 * u + 1] * se + r4.y;
        od[4 * u + 2] = oacc1[4 * u + 2] * se + r4.z;
        od[4 * u + 3] = oacc1[4 * u + 3] * se + r4.w;
      }
    }
    int n = qt * 64 + 32 * p + c;
    int colbase = h * 64 + 32 * e + 4 * hi;
#pragma unroll
    for (int jj = 0; jj < 4; ++jj) {
      u64 pk = (u64)f2bf(od[4 * jj] * rdiv) |
               ((u64)f2bf(od[4 * jj + 1] * rdiv) << 16) |
               ((u64)f2bf(od[4 * jj + 2] * rdiv) << 32) |
               ((u64)f2bf(od[4 * jj + 3] * rdiv) << 48);
      *(u64*)&OH[((size_t)b * 1024 + n) * 768 + colbase + 8 * jj] = pk;
    }
  }
}

static inline int cvtblocks(int n4) {
  int nb = (n4 + 255) / 256;
  return nb > 2048 ? 2048 : nb;
}

extern "C" void kernel_launch(void* const* d_in, const int* in_sizes, int n_in,
                              void* d_out, int out_size, void* d_ws, size_t ws_size,
                              hipStream_t stream) {
  (void)in_sizes; (void)n_in; (void)out_size; (void)ws_size;
  const float* x = (const float*)d_in[0];
  const float* Wq = (const float*)d_in[1];
  const float* Wk = (const float*)d_in[2];
  const float* Wv = (const float*)d_in[3];
  const float* bv = (const float*)d_in[4];
  const float* Wmix = (const float*)d_in[5];
  const float* Wcb = (const float*)d_in[6];
  const float* Wproj = (const float*)d_in[7];
  const float* bproj = (const float*)d_in[8];
  float* out = (float*)d_out;

  char* ws = (char*)d_ws;
  u16* xbf = (u16*)(ws);                 // 12582912 B
  u16* Wqk = (u16*)(ws + 12582912);      // 2359296 B
  u16* Wvcb = (u16*)(ws + 14942208);     // 1376256 B
  u16* Wpj = (u16*)(ws + 16318464);      // 1179648 B
  u16* QKb = (u16*)(ws + 17498112);      // 25165824 B
  u16* vT = (u16*)(ws + 42663936);       // 12582912 B
  float* cbb = (float*)(ws + 55246848);  // 393216 B
  u16* OH = (u16*)(ws + 55640064);       // 12582912 B

  cvt_f32_bf16<<<cvtblocks(1572864), 256, 0, stream>>>((const float4*)x, (uint2*)xbf, 1572864);
  cvt_f32_bf16<<<cvtblocks(147456), 256, 0, stream>>>((const float4*)Wq, (uint2*)Wqk, 147456);
  cvt_f32_bf16<<<cvtblocks(147456), 256, 0, stream>>>((const float4*)Wk, (uint2*)(Wqk + 589824), 147456);
  cvt_f32_bf16<<<cvtblocks(147456), 256, 0, stream>>>((const float4*)Wv, (uint2*)Wvcb, 147456);
  cvt_f32_bf16<<<cvtblocks(2304), 256, 0, stream>>>((const float4*)Wcb, (uint2*)(Wvcb + 589824), 2304);
  cvt_f32_bf16<<<cvtblocks(147456), 256, 0, stream>>>((const float4*)Wproj, (uint2*)Wpj, 147456);

  gemm_bt<0><<<dim3(12, 64), 256, 0, stream>>>(xbf, Wqk, QKb, nullptr, nullptr, 1536);
  gemm_bt<1><<<dim3(64, 7), 256, 0, stream>>>(Wvcb, xbf, vT, cbb, bv, 0);
  attn5<<<dim3(8, 12, 16), 256, 0, stream>>>(QKb, vT, cbb, Wmix, OH);
  gemm_bt<2><<<dim3(6, 64), 256, 0, stream>>>(OH, Wpj, out, nullptr, bproj, 768);
}

// Round 6
// 335.613 us; speedup vs baseline: 1.6196x; 1.2166x over previous
//
#include <hip/hip_runtime.h>
#include <stdint.h>

typedef unsigned short u16;
typedef unsigned char u8;
typedef unsigned long long u64;
typedef __attribute__((ext_vector_type(8))) short bf16x8;
typedef __attribute__((ext_vector_type(4))) float f32x4;

#define KLOG2E 0.18033688011112043f   // SCALE(0.125) * log2(e)
#define QSCL 184.66496523378732f      // KLOG2E * 1024
#define SINV 0.0001220703125f         // 2^-13
#define EXP2F(x) __builtin_amdgcn_exp2f(x)

__device__ __forceinline__ u16 f2bf(float f) {
  union { float f; unsigned u; } v; v.f = f;
  unsigned r = v.u + 0x7fffu + ((v.u >> 16) & 1u);
  return (u16)(r >> 16);
}
__device__ __forceinline__ float bf2f(u16 u) {
  union { unsigned u; float f; } v; v.u = ((unsigned)u) << 16;
  return v.f;
}
__device__ __forceinline__ u8 f2fp8(float f) {
  return (u8)(__builtin_amdgcn_cvt_pk_fp8_f32(f, f, 0, false) & 0xFF);
}
__device__ __forceinline__ long pk64(uint2 v) {
  return (long)(((u64)v.y << 32) | (u64)v.x);
}

__device__ __forceinline__ void gload16(const void* g, void* l) {
  __builtin_amdgcn_global_load_lds(
      (const __attribute__((address_space(1))) unsigned int*)g,
      (__attribute__((address_space(3))) unsigned int*)l, 16, 0, 0);
}

__global__ void cvt_f32_bf16(const float4* __restrict__ s, uint2* __restrict__ d, int n4) {
  int i = blockIdx.x * blockDim.x + threadIdx.x;
  int stride = gridDim.x * blockDim.x;
  for (; i < n4; i += stride) {
    float4 v = s[i];
    uint2 o;
    o.x = (unsigned)f2bf(v.x) | ((unsigned)f2bf(v.y) << 16);
    o.y = (unsigned)f2bf(v.z) | ((unsigned)f2bf(v.w) << 16);
    d[i] = o;
  }
}

// C = A @ B^T, A [M,768] bf16, B [N,768] bf16, 128x128 tile, 4 waves.
// MODE 0: col<768 -> Qb bf16 [row][768]; col>=768 -> Kf8 fp8(x8) [row][768]
// MODE 1: vT+cb store (A rows: 0-767 -> vT bf16 +bias, 768-779 -> cb f32 pre-scaled)
// MODE 2: f32 C store + bias[col], ldc given.
template <int MODE>
__global__ __launch_bounds__(256, 2) void gemm_bt(
    const u16* __restrict__ A, const u16* __restrict__ Bm,
    void* __restrict__ Cp, void* __restrict__ Cp2,
    const float* __restrict__ bias, int ldc) {
  __shared__ u16 Ab[128 * 32];
  __shared__ u16 Bb[128 * 32];
  const int tid = threadIdx.x;
  const int l = tid & 63, w = tid >> 6;
  const int g = l >> 4, l15 = l & 15;
  const int wr = w >> 1, wc = w & 1;
  const int rowbase = blockIdx.y * 128, colbase = blockIdx.x * 128;

  f32x4 acc[4][4] = {};
  const char* Abase = (const char*)A + (size_t)rowbase * 1536;
  const char* Bbase = (const char*)Bm + (size_t)colbase * 1536;

  for (int kk = 0; kk < 768; kk += 32) {
    __syncthreads();
#pragma unroll
    for (int p = 0; p < 2; ++p) {
      int o = p * 4096 + w * 1024 + l * 16;
      int row = o >> 6, cb = o & 63;
      gload16(Abase + (size_t)row * 1536 + kk * 2 + cb, &Ab[(p * 4096 + w * 1024) / 2]);
      gload16(Bbase + (size_t)row * 1536 + kk * 2 + cb, &Bb[(p * 4096 + w * 1024) / 2]);
    }
    __syncthreads();
    bf16x8 af[4], bfr[4];
#pragma unroll
    for (int i = 0; i < 4; ++i) {
      af[i] = *(const bf16x8*)&Ab[(wr * 64 + i * 16 + l15) * 32 + g * 8];
      bfr[i] = *(const bf16x8*)&Bb[(wc * 64 + i * 16 + l15) * 32 + g * 8];
    }
#pragma unroll
    for (int mi = 0; mi < 4; ++mi)
#pragma unroll
      for (int ni = 0; ni < 4; ++ni)
        acc[mi][ni] = __builtin_amdgcn_mfma_f32_16x16x32_bf16(af[mi], bfr[ni], acc[mi][ni], 0, 0, 0);
  }

#pragma unroll
  for (int mi = 0; mi < 4; ++mi)
#pragma unroll
    for (int ni = 0; ni < 4; ++ni)
#pragma unroll
      for (int r = 0; r < 4; ++r) {
        int row = rowbase + wr * 64 + mi * 16 + g * 4 + r;
        int col = colbase + wc * 64 + ni * 16 + l15;
        float v = acc[mi][ni][r];
        if (MODE == 0) {
          if (col < 768)
            ((u16*)Cp)[(size_t)row * 768 + col] = f2bf(v);
          else
            ((u8*)Cp2)[(size_t)row * 768 + (col - 768)] = f2fp8(v * 8.0f);
        } else if (MODE == 2) {
          ((float*)Cp)[(size_t)row * ldc + col] = v + bias[col];
        } else {
          int b = col >> 10, nn = col & 1023;
          if (row < 768) {
            ((u16*)Cp)[(size_t)b * 786432 + (size_t)row * 1024 + nn] = f2bf(v + bias[row]);
          } else if (row < 780) {
            ((float*)Cp2)[(size_t)b * 12288 + (size_t)(row - 768) * 1024 + nn] = v * KLOG2E;
          }
        }
      }
}

// Flash attention v6: fp8 QK^T (full-768d Q in 48 VGPR per wave), Nq=16/wave,
// no cross-wave exchange. grid (b=8, h=12, qt=16), 256 threads, 4 blocks/CU.
__global__ __launch_bounds__(256, 4) void attn6(
    const u16* __restrict__ Qb,   // [B*N][768] bf16 (q_shared)
    const u8* __restrict__ Kf8,   // [B*N][768] fp8 e4m3, x8
    const u16* __restrict__ vT,   // [B][768][1024] bf16
    const float* __restrict__ cb, // [B][12][1024], pre-scaled by KLOG2E
    const float* __restrict__ Wmix,
    u16* __restrict__ OH)         // [B*N][768] bf16
{
  __shared__ u8 Kb[2][8192];    // dbuf: 64 k-rows x 128B (128-d fp8 chunk), 16B-slot swz
  __shared__ u16 Vb[2][4096];   // dbuf: [kwin2][64 d][4 slots x 16B] (64 k bf16)
  __shared__ u16 Pb[4][1024];   // per-wave P: [16 q][64 k] bf16, 16B-slot swz

  const int b = blockIdx.x, h = blockIdx.y, qt = blockIdx.z;
  const int tid = threadIdx.x;
  const int l = tid & 63, w = tid >> 6;
  const int g = l >> 4, l15 = l & 15;

  const u8* Ksrc = Kf8 + (size_t)b * 786432;
  const char* Vsrc = (const char*)vT + (size_t)(b * 12 + h) * 131072;
  const float* cbp = cb + (size_t)(b * 12 + h) * 1024;

  // ---- Q prologue: load 16 q-rows x 768 d, multiply by Wmix*KLOG2E*1024, quantize fp8
  uint2 qreg[24];
  {
    const u16* qrow = Qb + ((size_t)b * 1024 + qt * 64 + w * 16 + l15) * 768;
    const float* wmh = Wmix + h * 768;
#pragma unroll
    for (int wd = 0; wd < 24; ++wd) {
      bf16x8 qv = *(const bf16x8*)(qrow + wd * 32 + g * 8);
      const float* wm = wmh + wd * 32 + g * 8;
      float4 w0 = *(const float4*)wm;
      float4 w1 = *(const float4*)(wm + 4);
      float q0 = bf2f((u16)qv[0]) * (w0.x * QSCL);
      float q1 = bf2f((u16)qv[1]) * (w0.y * QSCL);
      float q2 = bf2f((u16)qv[2]) * (w0.z * QSCL);
      float q3 = bf2f((u16)qv[3]) * (w0.w * QSCL);
      float q4 = bf2f((u16)qv[4]) * (w1.x * QSCL);
      float q5 = bf2f((u16)qv[5]) * (w1.y * QSCL);
      float q6 = bf2f((u16)qv[6]) * (w1.z * QSCL);
      float q7 = bf2f((u16)qv[7]) * (w1.w * QSCL);
      int a = __builtin_amdgcn_cvt_pk_fp8_f32(q0, q1, 0, false);
      a = __builtin_amdgcn_cvt_pk_fp8_f32(q2, q3, a, true);
      int b2 = __builtin_amdgcn_cvt_pk_fp8_f32(q4, q5, 0, false);
      b2 = __builtin_amdgcn_cvt_pk_fp8_f32(q6, q7, b2, true);
      qreg[wd].x = (unsigned)a;
      qreg[wd].y = (unsigned)b2;
    }
  }

  auto STK = [&](int kt, int ch, int buf) {
#pragma unroll
    for (int p4 = 0; p4 < 2; ++p4) {
      int o = p4 * 4096 + tid * 16;
      int row = o >> 7, t = (o >> 4) & 7;
      gload16(Ksrc + (size_t)(kt * 64 + row) * 768 + ch * 128 + ((t ^ (row & 7)) * 16),
              (char*)Kb[buf] + o);
    }
  };
  auto STV = [&](int kt, int buf) {
#pragma unroll
    for (int p4 = 0; p4 < 2; ++p4) {
      int o = p4 * 4096 + tid * 16;
      int kwin = o >> 12, o2 = o & 4095, d = o2 >> 6, s = (o2 >> 4) & 3;
      gload16(Vsrc + (size_t)d * 2048 + (kt * 64 + kwin * 32 + ((s ^ (d & 3)) * 8)) * 2,
              (char*)Vb[buf] + o);
    }
  };

  float m_run = -1e30f, lpart = 0.f;
  f32x4 oacc[4] = {};
  STK(0, 0, 0);
  STV(0, 0);
  __syncthreads();
  int kb = 0, vph = 0;

  for (int kt = 0; kt < 16; ++kt) {
    f32x4 sa[4] = {};
#pragma unroll
    for (int ch = 0; ch < 6; ++ch) {
      if (ch < 5) STK(kt, ch + 1, kb ^ 1);
      else if (kt < 15) STK(kt + 1, 0, kb ^ 1);
      if (ch == 1 && kt < 15) STV(kt + 1, vph ^ 1);
#pragma unroll
      for (int w4 = 0; w4 < 4; ++w4) {
        long qf = pk64(qreg[ch * 4 + w4]);
#pragma unroll
        for (int s = 0; s < 4; ++s) {
          int u = (4 * w4 + g) ^ ((l15 & 7) << 1);
          uint2 kk = *(const uint2*)&Kb[kb][(16 * s + l15) * 128 + u * 8];
          sa[s] = __builtin_amdgcn_mfma_f32_16x16x32_fp8_fp8(pk64(kk), qf, sa[s], 0, 0, 0);
        }
      }
      __syncthreads();
      kb ^= 1;
    }

    // ---- softmax: lane holds rows k = 16s+4g+r for column q = l15
    float fv[16];
    float pmax = -1e30f;
#pragma unroll
    for (int s = 0; s < 4; ++s) {
      float4 cbv = *(const float4*)(cbp + kt * 64 + s * 16 + g * 4);
      fv[s * 4 + 0] = fmaf(sa[s][0], SINV, cbv.x);
      fv[s * 4 + 1] = fmaf(sa[s][1], SINV, cbv.y);
      fv[s * 4 + 2] = fmaf(sa[s][2], SINV, cbv.z);
      fv[s * 4 + 3] = fmaf(sa[s][3], SINV, cbv.w);
#pragma unroll
      for (int r = 0; r < 4; ++r) pmax = fmaxf(pmax, fv[s * 4 + r]);
    }
    pmax = fmaxf(pmax, __shfl_xor(pmax, 16));
    pmax = fmaxf(pmax, __shfl_xor(pmax, 32));
    if (__ballot(pmax > m_run)) {
      float mnew = fmaxf(m_run, pmax);
      float alpha = EXP2F(m_run - mnew);
      lpart *= alpha;
#pragma unroll
      for (int vf = 0; vf < 4; ++vf) oacc[vf] *= alpha;
      m_run = mnew;
    }
    float rs = 0.f;
#pragma unroll
    for (int r = 0; r < 16; ++r) {
      fv[r] = EXP2F(fv[r] - m_run);
      rs += fv[r];
    }
    rs += __shfl_xor(rs, 16);
    rs += __shfl_xor(rs, 32);
    lpart += rs;

    // ---- P pack -> per-wave LDS [q][k] (b64 writes, 16B-slot swz)
#pragma unroll
    for (int s = 0; s < 4; ++s) {
      unsigned w01, w23;
      asm("v_cvt_pk_bf16_f32 %0, %1, %2" : "=v"(w01) : "v"(fv[s * 4]), "v"(fv[s * 4 + 1]));
      asm("v_cvt_pk_bf16_f32 %0, %1, %2" : "=v"(w23) : "v"(fv[s * 4 + 2]), "v"(fv[s * 4 + 3]));
      int ts = (2 * s + (g >> 1)) ^ (l15 & 7);
      uint2 uu; uu.x = w01; uu.y = w23;
      *(uint2*)((char*)Pb[w] + l15 * 128 + ts * 16 + (g & 1) * 8) = uu;
    }

    // ---- PV: A = V (16d x 32k) from LDS, B = P from LDS
#pragma unroll
    for (int kwin = 0; kwin < 2; ++kwin) {
      int tr = (4 * kwin + g) ^ (l15 & 7);
      bf16x8 pf = *(const bf16x8*)((const char*)Pb[w] + l15 * 128 + tr * 16);
#pragma unroll
      for (int vf = 0; vf < 4; ++vf) {
        int d = vf * 16 + l15;
        bf16x8 vfrag = *(const bf16x8*)((const char*)Vb[vph] + kwin * 4096 + d * 64 +
                                        ((g ^ (d & 3)) * 16));
        oacc[vf] = __builtin_amdgcn_mfma_f32_16x16x32_bf16(vfrag, pf, oacc[vf], 0, 0, 0);
      }
    }
    vph ^= 1;
  }

  // ---- epilogue: lane (q=l15) holds d = vf*16+4g+r; divide by l, store packed u64
  float rdiv = 1.f / lpart;
  size_t nrow = ((size_t)b * 1024 + qt * 64 + w * 16 + l15) * 768;
#pragma unroll
  for (int vf = 0; vf < 4; ++vf) {
    u64 pk = (u64)f2bf(oacc[vf][0] * rdiv) |
             ((u64)f2bf(oacc[vf][1] * rdiv) << 16) |
             ((u64)f2bf(oacc[vf][2] * rdiv) << 32) |
             ((u64)f2bf(oacc[vf][3] * rdiv) << 48);
    *(u64*)&OH[nrow + h * 64 + vf * 16 + 4 * g] = pk;
  }
}

static inline int cvtblocks(int n4) {
  int nb = (n4 + 255) / 256;
  return nb > 2048 ? 2048 : nb;
}

extern "C" void kernel_launch(void* const* d_in, const int* in_sizes, int n_in,
                              void* d_out, int out_size, void* d_ws, size_t ws_size,
                              hipStream_t stream) {
  (void)in_sizes; (void)n_in; (void)out_size; (void)ws_size;
  const float* x = (const float*)d_in[0];
  const float* Wq = (const float*)d_in[1];
  const float* Wk = (const float*)d_in[2];
  const float* Wv = (const float*)d_in[3];
  const float* bv = (const float*)d_in[4];
  const float* Wmix = (const float*)d_in[5];
  const float* Wcb = (const float*)d_in[6];
  const float* Wproj = (const float*)d_in[7];
  const float* bproj = (const float*)d_in[8];
  float* out = (float*)d_out;

  char* ws = (char*)d_ws;
  u16* xbf = (u16*)(ws);                 // 12582912 B
  u16* Wqk = (u16*)(ws + 12582912);      // 2359296 B
  u16* Wvcb = (u16*)(ws + 14942208);     // 1376256 B
  u16* Wpj = (u16*)(ws + 16318464);      // 1179648 B
  u16* Qb = (u16*)(ws + 17498112);       // 12582912 B
  u8* Kf8 = (u8*)(ws + 30081024);        // 6291456 B
  u16* vT = (u16*)(ws + 36372480);       // 12582912 B
  float* cbb = (float*)(ws + 48955392);  // 393216 B
  u16* OH = (u16*)(ws + 49348608);       // 12582912 B (end 61931520)

  cvt_f32_bf16<<<cvtblocks(1572864), 256, 0, stream>>>((const float4*)x, (uint2*)xbf, 1572864);
  cvt_f32_bf16<<<cvtblocks(147456), 256, 0, stream>>>((const float4*)Wq, (uint2*)Wqk, 147456);
  cvt_f32_bf16<<<cvtblocks(147456), 256, 0, stream>>>((const float4*)Wk, (uint2*)(Wqk + 589824), 147456);
  cvt_f32_bf16<<<cvtblocks(147456), 256, 0, stream>>>((const float4*)Wv, (uint2*)Wvcb, 147456);
  cvt_f32_bf16<<<cvtblocks(2304), 256, 0, stream>>>((const float4*)Wcb, (uint2*)(Wvcb + 589824), 2304);
  cvt_f32_bf16<<<cvtblocks(147456), 256, 0, stream>>>((const float4*)Wproj, (uint2*)Wpj, 147456);

  gemm_bt<0><<<dim3(12, 64), 256, 0, stream>>>(xbf, Wqk, Qb, Kf8, nullptr, 0);
  gemm_bt<1><<<dim3(64, 7), 256, 0, stream>>>(Wvcb, xbf, vT, cbb, bv, 0);
  attn6<<<dim3(8, 12, 16), 256, 0, stream>>>(Qb, Kf8, vT, cbb, Wmix, OH);
  gemm_bt<2><<<dim3(6, 64), 256, 0, stream>>>(OH, Wpj, out, nullptr, bproj, 768);
}

// Round 7
// 331.472 us; speedup vs baseline: 1.6399x; 1.0125x over previous
//
#include <hip/hip_runtime.h>
#include <stdint.h>

typedef unsigned short u16;
typedef unsigned char u8;
typedef unsigned long long u64;
typedef __attribute__((ext_vector_type(8))) short bf16x8;
typedef __attribute__((ext_vector_type(4))) float f32x4;

#define KLOG2E 0.18033688011112043f   // SCALE(0.125) * log2(e)
#define QSCL 184.66496523378732f      // KLOG2E * 1024
#define SINV 0.0001220703125f         // 2^-13
#define EXP2F(x) __builtin_amdgcn_exp2f(x)

__device__ __forceinline__ u16 f2bf(float f) {
  union { float f; unsigned u; } v; v.f = f;
  unsigned r = v.u + 0x7fffu + ((v.u >> 16) & 1u);
  return (u16)(r >> 16);
}
__device__ __forceinline__ float bf2f(u16 u) {
  union { unsigned u; float f; } v; v.u = ((unsigned)u) << 16;
  return v.f;
}
__device__ __forceinline__ u8 f2fp8(float f) {
  return (u8)(__builtin_amdgcn_cvt_pk_fp8_f32(f, f, 0, false) & 0xFF);
}
__device__ __forceinline__ long pk64(uint2 v) {
  return (long)(((u64)v.y << 32) | (u64)v.x);
}

__device__ __forceinline__ void gload16(const void* g, void* l) {
  __builtin_amdgcn_global_load_lds(
      (const __attribute__((address_space(1))) unsigned int*)g,
      (__attribute__((address_space(3))) unsigned int*)l, 16, 0, 0);
}

__global__ void cvt_f32_bf16(const float4* __restrict__ s, uint2* __restrict__ d, int n4) {
  int i = blockIdx.x * blockDim.x + threadIdx.x;
  int stride = gridDim.x * blockDim.x;
  for (; i < n4; i += stride) {
    float4 v = s[i];
    uint2 o;
    o.x = (unsigned)f2bf(v.x) | ((unsigned)f2bf(v.y) << 16);
    o.y = (unsigned)f2bf(v.z) | ((unsigned)f2bf(v.w) << 16);
    d[i] = o;
  }
}

// C = A @ B^T, A [M,768] bf16, B [N,768] bf16, 128x128 tile, 4 waves.
// MODE 0: col<768 -> Qb bf16 [row][768]; col>=768 -> Kf8 fp8 x8, PERMUTED dim order
// MODE 1: vT+cb store; MODE 2: f32 C + bias[col].
template <int MODE>
__global__ __launch_bounds__(256, 2) void gemm_bt(
    const u16* __restrict__ A, const u16* __restrict__ Bm,
    void* __restrict__ Cp, void* __restrict__ Cp2,
    const float* __restrict__ bias, int ldc) {
  __shared__ u16 Ab[128 * 32];
  __shared__ u16 Bb[128 * 32];
  const int tid = threadIdx.x;
  const int l = tid & 63, w = tid >> 6;
  const int g = l >> 4, l15 = l & 15;
  const int wr = w >> 1, wc = w & 1;
  const int rowbase = blockIdx.y * 128, colbase = blockIdx.x * 128;

  f32x4 acc[4][4] = {};
  const char* Abase = (const char*)A + (size_t)rowbase * 1536;
  const char* Bbase = (const char*)Bm + (size_t)colbase * 1536;

  for (int kk = 0; kk < 768; kk += 32) {
    __syncthreads();
#pragma unroll
    for (int p = 0; p < 2; ++p) {
      int o = p * 4096 + w * 1024 + l * 16;
      int row = o >> 6, cb = o & 63;
      gload16(Abase + (size_t)row * 1536 + kk * 2 + cb, &Ab[(p * 4096 + w * 1024) / 2]);
      gload16(Bbase + (size_t)row * 1536 + kk * 2 + cb, &Bb[(p * 4096 + w * 1024) / 2]);
    }
    __syncthreads();
    bf16x8 af[4], bfr[4];
#pragma unroll
    for (int i = 0; i < 4; ++i) {
      af[i] = *(const bf16x8*)&Ab[(wr * 64 + i * 16 + l15) * 32 + g * 8];
      bfr[i] = *(const bf16x8*)&Bb[(wc * 64 + i * 16 + l15) * 32 + g * 8];
    }
#pragma unroll
    for (int mi = 0; mi < 4; ++mi)
#pragma unroll
      for (int ni = 0; ni < 4; ++ni)
        acc[mi][ni] = __builtin_amdgcn_mfma_f32_16x16x32_bf16(af[mi], bfr[ni], acc[mi][ni], 0, 0, 0);
  }

#pragma unroll
  for (int mi = 0; mi < 4; ++mi)
#pragma unroll
    for (int ni = 0; ni < 4; ++ni)
#pragma unroll
      for (int r = 0; r < 4; ++r) {
        int row = rowbase + wr * 64 + mi * 16 + g * 4 + r;
        int col = colbase + wc * 64 + ni * 16 + l15;
        float v = acc[mi][ni][r];
        if (MODE == 0) {
          if (col < 768) {
            ((u16*)Cp)[(size_t)row * 768 + col] = f2bf(v);
          } else {
            int d = col - 768;
            int chunk = d >> 7, w4 = (d >> 5) & 3, gg = (d >> 3) & 3, rr = d & 7;
            int dp = chunk * 128 + gg * 32 + w4 * 8 + rr;
            ((u8*)Cp2)[(size_t)row * 768 + dp] = f2fp8(v * 8.0f);
          }
        } else if (MODE == 2) {
          ((float*)Cp)[(size_t)row * ldc + col] = v + bias[col];
        } else {
          int b = col >> 10, nn = col & 1023;
          if (row < 768) {
            ((u16*)Cp)[(size_t)b * 786432 + (size_t)row * 1024 + nn] = f2bf(v + bias[row]);
          } else if (row < 780) {
            ((float*)Cp2)[(size_t)b * 12288 + (size_t)(row - 768) * 1024 + nn] = v * KLOG2E;
          }
        }
      }
}

// Flash attention v7: fp8 QK^T, Nq=16/wave, 8 waves (128 q) per block,
// b128 K fragment reads via permuted Kf8. grid (b=8, h=12, qt=8), 512 thr.
__global__ __launch_bounds__(512, 6) void attn7(
    const u16* __restrict__ Qb,   // [B*N][768] bf16 (q_shared)
    const u8* __restrict__ Kf8,   // [B*N][768] fp8 e4m3 x8, permuted dims
    const u16* __restrict__ vT,   // [B][768][1024] bf16
    const float* __restrict__ cb, // [B][12][1024], pre-scaled by KLOG2E
    const float* __restrict__ Wmix,
    u16* __restrict__ OH)         // [B*N][768] bf16
{
  __shared__ u8 Kb[2][8192];    // dbuf: 64 k-rows x 128B fp8 chunk, 16B-slot swz
  __shared__ u16 Vb[2][4096];   // dbuf: [kwin2][64 d][4 slots x 16B]
  __shared__ u16 Pb[8][1024];   // per-wave P: [16 q][64 k] bf16, swz

  const int b = blockIdx.x, h = blockIdx.y, qt = blockIdx.z;
  const int tid = threadIdx.x;
  const int l = tid & 63, w = tid >> 6;
  const int g = l >> 4, l15 = l & 15;

  const u8* Ksrc = Kf8 + (size_t)b * 786432;
  const char* Vsrc = (const char*)vT + (size_t)(b * 12 + h) * 131072;
  const float* cbp = cb + (size_t)(b * 12 + h) * 1024;

  // ---- Q prologue: 16 q-rows x 768 d, x(Wmix*KLOG2E*1024), quantize fp8
  uint2 qreg[24];
  {
    const u16* qrow = Qb + ((size_t)b * 1024 + qt * 128 + w * 16 + l15) * 768;
    const float* wmh = Wmix + h * 768;
#pragma unroll
    for (int wd = 0; wd < 24; ++wd) {
      bf16x8 qv = *(const bf16x8*)(qrow + wd * 32 + g * 8);
      const float* wm = wmh + wd * 32 + g * 8;
      float4 w0 = *(const float4*)wm;
      float4 w1 = *(const float4*)(wm + 4);
      float q0 = bf2f((u16)qv[0]) * (w0.x * QSCL);
      float q1 = bf2f((u16)qv[1]) * (w0.y * QSCL);
      float q2 = bf2f((u16)qv[2]) * (w0.z * QSCL);
      float q3 = bf2f((u16)qv[3]) * (w0.w * QSCL);
      float q4 = bf2f((u16)qv[4]) * (w1.x * QSCL);
      float q5 = bf2f((u16)qv[5]) * (w1.y * QSCL);
      float q6 = bf2f((u16)qv[6]) * (w1.z * QSCL);
      float q7 = bf2f((u16)qv[7]) * (w1.w * QSCL);
      int a = __builtin_amdgcn_cvt_pk_fp8_f32(q0, q1, 0, false);
      a = __builtin_amdgcn_cvt_pk_fp8_f32(q2, q3, a, true);
      int b2 = __builtin_amdgcn_cvt_pk_fp8_f32(q4, q5, 0, false);
      b2 = __builtin_amdgcn_cvt_pk_fp8_f32(q6, q7, b2, true);
      qreg[wd].x = (unsigned)a;
      qreg[wd].y = (unsigned)b2;
    }
  }

  auto STK = [&](int kt, int ch, int buf) {
    int o = tid * 16;  // 512 thr x 16B = 8192B
    int row = o >> 7, t = (o >> 4) & 7;
    gload16(Ksrc + (size_t)(kt * 64 + row) * 768 + ch * 128 + ((t ^ (row & 7)) * 16),
            (char*)Kb[buf] + o);
  };
  auto STV = [&](int kt, int buf) {
    int o = tid * 16;
    int kwin = o >> 12, o2 = o & 4095, d = o2 >> 6, s = (o2 >> 4) & 3;
    gload16(Vsrc + (size_t)d * 2048 + (kt * 64 + kwin * 32 + ((s ^ (d & 3)) * 8)) * 2,
            (char*)Vb[buf] + o);
  };

  float m_run = -1e30f, lpart = 0.f;
  f32x4 oacc[4] = {};
  STK(0, 0, 0);
  STV(0, 0);
  __syncthreads();
  int kb = 0, vph = 0;

  for (int kt = 0; kt < 16; ++kt) {
    f32x4 sa[4] = {};
#pragma unroll
    for (int ch = 0; ch < 6; ++ch) {
      if (ch < 5) STK(kt, ch + 1, kb ^ 1);
      else if (kt < 15) STK(kt + 1, 0, kb ^ 1);
      if (ch == 1 && kt < 15) STV(kt + 1, vph ^ 1);
#pragma unroll
      for (int j = 0; j < 2; ++j) {
        long qf0 = pk64(qreg[ch * 4 + 2 * j]);
        long qf1 = pk64(qreg[ch * 4 + 2 * j + 1]);
        int slot = (2 * g + j) ^ (l15 & 7);
#pragma unroll
        for (int s = 0; s < 4; ++s) {
          uint4 kk = *(const uint4*)&Kb[kb][(16 * s + l15) * 128 + slot * 16];
          long klo = (long)(((u64)kk.y << 32) | kk.x);
          long khi = (long)(((u64)kk.w << 32) | kk.z);
          sa[s] = __builtin_amdgcn_mfma_f32_16x16x32_fp8_fp8(klo, qf0, sa[s], 0, 0, 0);
          sa[s] = __builtin_amdgcn_mfma_f32_16x16x32_fp8_fp8(khi, qf1, sa[s], 0, 0, 0);
        }
      }
      __syncthreads();
      kb ^= 1;
    }

    // ---- softmax: lane holds rows k = 16s+4g+r for column q = l15
    float fv[16];
    float pmax = -1e30f;
#pragma unroll
    for (int s = 0; s < 4; ++s) {
      float4 cbv = *(const float4*)(cbp + kt * 64 + s * 16 + g * 4);
      fv[s * 4 + 0] = fmaf(sa[s][0], SINV, cbv.x);
      fv[s * 4 + 1] = fmaf(sa[s][1], SINV, cbv.y);
      fv[s * 4 + 2] = fmaf(sa[s][2], SINV, cbv.z);
      fv[s * 4 + 3] = fmaf(sa[s][3], SINV, cbv.w);
#pragma unroll
      for (int r = 0; r < 4; ++r) pmax = fmaxf(pmax, fv[s * 4 + r]);
    }
    pmax = fmaxf(pmax, __shfl_xor(pmax, 16));
    pmax = fmaxf(pmax, __shfl_xor(pmax, 32));
    if (__ballot(pmax > m_run)) {
      float mnew = fmaxf(m_run, pmax);
      float alpha = EXP2F(m_run - mnew);
      lpart *= alpha;
#pragma unroll
      for (int vf = 0; vf < 4; ++vf) oacc[vf] *= alpha;
      m_run = mnew;
    }
    float rs = 0.f;
#pragma unroll
    for (int r = 0; r < 16; ++r) {
      fv[r] = EXP2F(fv[r] - m_run);
      rs += fv[r];
    }
    rs += __shfl_xor(rs, 16);
    rs += __shfl_xor(rs, 32);
    lpart += rs;

    // ---- P pack -> per-wave LDS (b64 writes, 16B-slot swz)
#pragma unroll
    for (int s = 0; s < 4; ++s) {
      unsigned w01, w23;
      asm("v_cvt_pk_bf16_f32 %0, %1, %2" : "=v"(w01) : "v"(fv[s * 4]), "v"(fv[s * 4 + 1]));
      asm("v_cvt_pk_bf16_f32 %0, %1, %2" : "=v"(w23) : "v"(fv[s * 4 + 2]), "v"(fv[s * 4 + 3]));
      int ts = (2 * s + (g >> 1)) ^ (l15 & 7);
      uint2 uu; uu.x = w01; uu.y = w23;
      *(uint2*)((char*)Pb[w] + l15 * 128 + ts * 16 + (g & 1) * 8) = uu;
    }

    // ---- PV: A = V (16d x 32k) from LDS, B = P from LDS
#pragma unroll
    for (int kwin = 0; kwin < 2; ++kwin) {
      int tr = (4 * kwin + g) ^ (l15 & 7);
      bf16x8 pf = *(const bf16x8*)((const char*)Pb[w] + l15 * 128 + tr * 16);
#pragma unroll
      for (int vf = 0; vf < 4; ++vf) {
        int d = vf * 16 + l15;
        bf16x8 vfrag = *(const bf16x8*)((const char*)Vb[vph] + kwin * 4096 + d * 64 +
                                        ((g ^ (d & 3)) * 16));
        oacc[vf] = __builtin_amdgcn_mfma_f32_16x16x32_bf16(vfrag, pf, oacc[vf], 0, 0, 0);
      }
    }
    vph ^= 1;
  }

  // ---- epilogue: lane (q=l15) holds d = vf*16+4g+r; divide by l, store u64
  float rdiv = 1.f / lpart;
  size_t nrow = ((size_t)b * 1024 + qt * 128 + w * 16 + l15) * 768;
#pragma unroll
  for (int vf = 0; vf < 4; ++vf) {
    u64 pk = (u64)f2bf(oacc[vf][0] * rdiv) |
             ((u64)f2bf(oacc[vf][1] * rdiv) << 16) |
             ((u64)f2bf(oacc[vf][2] * rdiv) << 32) |
             ((u64)f2bf(oacc[vf][3] * rdiv) << 48);
    *(u64*)&OH[nrow + h * 64 + vf * 16 + 4 * g] = pk;
  }
}

static inline int cvtblocks(int n4) {
  int nb = (n4 + 255) / 256;
  return nb > 2048 ? 2048 : nb;
}

extern "C" void kernel_launch(void* const* d_in, const int* in_sizes, int n_in,
                              void* d_out, int out_size, void* d_ws, size_t ws_size,
                              hipStream_t stream) {
  (void)in_sizes; (void)n_in; (void)out_size; (void)ws_size;
  const float* x = (const float*)d_in[0];
  const float* Wq = (const float*)d_in[1];
  const float* Wk = (const float*)d_in[2];
  const float* Wv = (const float*)d_in[3];
  const float* bv = (const float*)d_in[4];
  const float* Wmix = (const float*)d_in[5];
  const float* Wcb = (const float*)d_in[6];
  const float* Wproj = (const float*)d_in[7];
  const float* bproj = (const float*)d_in[8];
  float* out = (float*)d_out;

  char* ws = (char*)d_ws;
  u16* xbf = (u16*)(ws);                 // 12582912 B
  u16* Wqk = (u16*)(ws + 12582912);      // 2359296 B
  u16* Wvcb = (u16*)(ws + 14942208);     // 1376256 B
  u16* Wpj = (u16*)(ws + 16318464);      // 1179648 B
  u16* Qb = (u16*)(ws + 17498112);       // 12582912 B
  u8* Kf8 = (u8*)(ws + 30081024);        // 6291456 B
  u16* vT = (u16*)(ws + 36372480);       // 12582912 B
  float* cbb = (float*)(ws + 48955392);  // 393216 B
  u16* OH = (u16*)(ws + 49348608);       // 12582912 B (end 61931520)

  cvt_f32_bf16<<<cvtblocks(1572864), 256, 0, stream>>>((const float4*)x, (uint2*)xbf, 1572864);
  cvt_f32_bf16<<<cvtblocks(147456), 256, 0, stream>>>((const float4*)Wq, (uint2*)Wqk, 147456);
  cvt_f32_bf16<<<cvtblocks(147456), 256, 0, stream>>>((const float4*)Wk, (uint2*)(Wqk + 589824), 147456);
  cvt_f32_bf16<<<cvtblocks(147456), 256, 0, stream>>>((const float4*)Wv, (uint2*)Wvcb, 147456);
  cvt_f32_bf16<<<cvtblocks(2304), 256, 0, stream>>>((const float4*)Wcb, (uint2*)(Wvcb + 589824), 2304);
  cvt_f32_bf16<<<cvtblocks(147456), 256, 0, stream>>>((const float4*)Wproj, (uint2*)Wpj, 147456);

  gemm_bt<0><<<dim3(12, 64), 256, 0, stream>>>(xbf, Wqk, Qb, Kf8, nullptr, 0);
  gemm_bt<1><<<dim3(64, 7), 256, 0, stream>>>(Wvcb, xbf, vT, cbb, bv, 0);
  attn7<<<dim3(8, 12, 8), 512, 0, stream>>>(Qb, Kf8, vT, cbb, Wmix, OH);
  gemm_bt<2><<<dim3(6, 64), 256, 0, stream>>>(OH, Wpj, out, nullptr, bproj, 768);
}

// Round 8
// 246.194 us; speedup vs baseline: 2.2079x; 1.3464x over previous
//
#include <hip/hip_runtime.h>
#include <stdint.h>

typedef unsigned short u16;
typedef unsigned char u8;
typedef unsigned long long u64;
typedef __attribute__((ext_vector_type(8))) short bf16x8;
typedef __attribute__((ext_vector_type(4))) float f32x4;

#define KLOG2E 0.18033688011112043f   // SCALE(0.125) * log2(e)
#define QSCL 184.66496523378732f      // KLOG2E * 1024
#define SINV 0.0001220703125f         // 2^-13
#define EXP2F(x) __builtin_amdgcn_exp2f(x)
#define WAITV(n) asm volatile("s_waitcnt vmcnt(" #n ")" ::: "memory")

__device__ __forceinline__ u16 f2bf(float f) {
  union { float f; unsigned u; } v; v.f = f;
  unsigned r = v.u + 0x7fffu + ((v.u >> 16) & 1u);
  return (u16)(r >> 16);
}
__device__ __forceinline__ float bf2f(u16 u) {
  union { unsigned u; float f; } v; v.u = ((unsigned)u) << 16;
  return v.f;
}
__device__ __forceinline__ u8 f2fp8(float f) {
  return (u8)(__builtin_amdgcn_cvt_pk_fp8_f32(f, f, 0, false) & 0xFF);
}
__device__ __forceinline__ long pk64(uint2 v) {
  return (long)(((u64)v.y << 32) | (u64)v.x);
}

__device__ __forceinline__ void gload16(const void* g, void* l) {
  __builtin_amdgcn_global_load_lds(
      (const __attribute__((address_space(1))) unsigned int*)g,
      (__attribute__((address_space(3))) unsigned int*)l, 16, 0, 0);
}

__global__ void cvt_f32_bf16(const float4* __restrict__ s, uint2* __restrict__ d, int n4) {
  int i = blockIdx.x * blockDim.x + threadIdx.x;
  int stride = gridDim.x * blockDim.x;
  for (; i < n4; i += stride) {
    float4 v = s[i];
    uint2 o;
    o.x = (unsigned)f2bf(v.x) | ((unsigned)f2bf(v.y) << 16);
    o.y = (unsigned)f2bf(v.z) | ((unsigned)f2bf(v.w) << 16);
    d[i] = o;
  }
}

// C = A @ B^T, A [M,768] bf16, B [N,768] bf16, 128x128 tile, 4 waves.
// MODE 0: col<768 -> Qb bf16 [row][768]; col>=768 -> Kf8 fp8 x8, PERMUTED dim order
// MODE 1: vT+cb store; MODE 2: f32 C + bias[col].
template <int MODE>
__global__ __launch_bounds__(256, 2) void gemm_bt(
    const u16* __restrict__ A, const u16* __restrict__ Bm,
    void* __restrict__ Cp, void* __restrict__ Cp2,
    const float* __restrict__ bias, int ldc) {
  __shared__ u16 Ab[128 * 32];
  __shared__ u16 Bb[128 * 32];
  const int tid = threadIdx.x;
  const int l = tid & 63, w = tid >> 6;
  const int g = l >> 4, l15 = l & 15;
  const int wr = w >> 1, wc = w & 1;
  const int rowbase = blockIdx.y * 128, colbase = blockIdx.x * 128;

  f32x4 acc[4][4] = {};
  const char* Abase = (const char*)A + (size_t)rowbase * 1536;
  const char* Bbase = (const char*)Bm + (size_t)colbase * 1536;

  for (int kk = 0; kk < 768; kk += 32) {
    __syncthreads();
#pragma unroll
    for (int p = 0; p < 2; ++p) {
      int o = p * 4096 + w * 1024 + l * 16;
      int row = o >> 6, cb = o & 63;
      gload16(Abase + (size_t)row * 1536 + kk * 2 + cb, &Ab[(p * 4096 + w * 1024) / 2]);
      gload16(Bbase + (size_t)row * 1536 + kk * 2 + cb, &Bb[(p * 4096 + w * 1024) / 2]);
    }
    __syncthreads();
    bf16x8 af[4], bfr[4];
#pragma unroll
    for (int i = 0; i < 4; ++i) {
      af[i] = *(const bf16x8*)&Ab[(wr * 64 + i * 16 + l15) * 32 + g * 8];
      bfr[i] = *(const bf16x8*)&Bb[(wc * 64 + i * 16 + l15) * 32 + g * 8];
    }
#pragma unroll
    for (int mi = 0; mi < 4; ++mi)
#pragma unroll
      for (int ni = 0; ni < 4; ++ni)
        acc[mi][ni] = __builtin_amdgcn_mfma_f32_16x16x32_bf16(af[mi], bfr[ni], acc[mi][ni], 0, 0, 0);
  }

#pragma unroll
  for (int mi = 0; mi < 4; ++mi)
#pragma unroll
    for (int ni = 0; ni < 4; ++ni)
#pragma unroll
      for (int r = 0; r < 4; ++r) {
        int row = rowbase + wr * 64 + mi * 16 + g * 4 + r;
        int col = colbase + wc * 64 + ni * 16 + l15;
        float v = acc[mi][ni][r];
        if (MODE == 0) {
          if (col < 768) {
            ((u16*)Cp)[(size_t)row * 768 + col] = f2bf(v);
          } else {
            int d = col - 768;
            int chunk = d >> 7, w4 = (d >> 5) & 3, gg = (d >> 3) & 3, rr = d & 7;
            int dp = chunk * 128 + gg * 32 + w4 * 8 + rr;
            ((u8*)Cp2)[(size_t)row * 768 + dp] = f2fp8(v * 8.0f);
          }
        } else if (MODE == 2) {
          ((float*)Cp)[(size_t)row * ldc + col] = v + bias[col];
        } else {
          int b = col >> 10, nn = col & 1023;
          if (row < 768) {
            ((u16*)Cp)[(size_t)b * 786432 + (size_t)row * 1024 + nn] = f2bf(v + bias[row]);
          } else if (row < 780) {
            ((float*)Cp2)[(size_t)b * 12288 + (size_t)(row - 768) * 1024 + nn] = v * KLOG2E;
          }
        }
      }
}

// Flash attention v8: fp8 QK^T, 8 waves x 16q, 3-deep K pipeline with counted
// vmcnt (no drain), setprio, XCD-bijective swizzle. grid 768 x 512 thr.
__global__ __launch_bounds__(512, 6) void attn8(
    const u16* __restrict__ Qb,   // [B*N][768] bf16 (q_shared)
    const u8* __restrict__ Kf8,   // [B*N][768] fp8 e4m3 x8, permuted dims
    const u16* __restrict__ vT,   // [B][768][1024] bf16
    const float* __restrict__ cb, // [B][12][1024], pre-scaled by KLOG2E
    const float* __restrict__ Wmix,
    u16* __restrict__ OH)         // [B*N][768] bf16
{
  __shared__ u8 Kb[3][8192];    // 3-deep: 64 k-rows x 128B fp8 chunk, 16B-slot swz
  __shared__ u16 Vb[2][4096];   // dbuf: [kwin2][64 d][4 slots x 16B]
  __shared__ u16 Pb[8][1024];   // per-wave P: [16 q][64 k] bf16, swz

  // XCD-bijective decode: XCD = gid&7 handles batch b = gid&7 exclusively.
  const int gid = blockIdx.x;
  const int b = gid & 7;
  const int within = gid >> 3;     // 0..95
  const int h = within % 12, qt = within / 12;  // qt 0..7
  const int tid = threadIdx.x;
  const int l = tid & 63, w = tid >> 6;
  const int g = l >> 4, l15 = l & 15;

  const u8* Ksrc = Kf8 + (size_t)b * 786432;
  const char* Vsrc = (const char*)vT + (size_t)(b * 12 + h) * 131072;
  const float* cbp = cb + (size_t)(b * 12 + h) * 1024;

  // ---- Q prologue: 16 q-rows x 768 d, x(Wmix*KLOG2E*1024), quantize fp8
  uint2 qreg[24];
  {
    const u16* qrow = Qb + ((size_t)b * 1024 + qt * 128 + w * 16 + l15) * 768;
    const float* wmh = Wmix + h * 768;
#pragma unroll
    for (int wd = 0; wd < 24; ++wd) {
      bf16x8 qv = *(const bf16x8*)(qrow + wd * 32 + g * 8);
      const float* wm = wmh + wd * 32 + g * 8;
      float4 w0 = *(const float4*)wm;
      float4 w1 = *(const float4*)(wm + 4);
      float q0 = bf2f((u16)qv[0]) * (w0.x * QSCL);
      float q1 = bf2f((u16)qv[1]) * (w0.y * QSCL);
      float q2 = bf2f((u16)qv[2]) * (w0.z * QSCL);
      float q3 = bf2f((u16)qv[3]) * (w0.w * QSCL);
      float q4 = bf2f((u16)qv[4]) * (w1.x * QSCL);
      float q5 = bf2f((u16)qv[5]) * (w1.y * QSCL);
      float q6 = bf2f((u16)qv[6]) * (w1.z * QSCL);
      float q7 = bf2f((u16)qv[7]) * (w1.w * QSCL);
      int a = __builtin_amdgcn_cvt_pk_fp8_f32(q0, q1, 0, false);
      a = __builtin_amdgcn_cvt_pk_fp8_f32(q2, q3, a, true);
      int b2 = __builtin_amdgcn_cvt_pk_fp8_f32(q4, q5, 0, false);
      b2 = __builtin_amdgcn_cvt_pk_fp8_f32(q6, q7, b2, true);
      qreg[wd].x = (unsigned)a;
      qreg[wd].y = (unsigned)b2;
    }
  }

  auto STK = [&](int kt, int ch, int buf) {
    int o = tid * 16;  // 512 thr x 16B = 8192B
    int row = o >> 7, t = (o >> 4) & 7;
    gload16(Ksrc + (size_t)(kt * 64 + row) * 768 + ch * 128 + ((t ^ (row & 7)) * 16),
            (char*)Kb[buf] + o);
  };
  auto STV = [&](int kt, int buf) {
    int o = tid * 16;
    int kwin = o >> 12, o2 = o & 4095, d = o2 >> 6, s = (o2 >> 4) & 3;
    gload16(Vsrc + (size_t)d * 2048 + (kt * 64 + kwin * 32 + ((s ^ (d & 3)) * 8)) * 2,
            (char*)Vb[buf] + o);
  };

  float m_run = -1e30f, lpart = 0.f;
  f32x4 oacc[4] = {};
  // prologue: stage phases 0,1 and V(kt0); single full drain
  STK(0, 0, 0);
  STK(0, 1, 1);
  STV(0, 0);
  __syncthreads();

  for (int kt = 0; kt < 16; ++kt) {
    f32x4 sa[4] = {};
#pragma unroll
    for (int ch = 0; ch < 6; ++ch) {
      // ---- stage (phase+2): V first at ch1 so it drains with W=2
      if (ch == 1 && kt < 15) STV(kt + 1, (kt + 1) & 1);
      if (ch <= 3) STK(kt, ch + 2, (ch + 2) % 3);
      else if (kt < 15) STK(kt + 1, ch - 4, (ch + 2) % 3);
      // ---- compute chunk ch from Kb[ch%3]
      __builtin_amdgcn_s_setprio(1);
#pragma unroll
      for (int j = 0; j < 2; ++j) {
        long qf0 = pk64(qreg[ch * 4 + 2 * j]);
        long qf1 = pk64(qreg[ch * 4 + 2 * j + 1]);
        int slot = (2 * g + j) ^ (l15 & 7);
#pragma unroll
        for (int s = 0; s < 4; ++s) {
          uint4 kk = *(const uint4*)&Kb[ch % 3][(16 * s + l15) * 128 + slot * 16];
          long klo = (long)(((u64)kk.y << 32) | kk.x);
          long khi = (long)(((u64)kk.w << 32) | kk.z);
          sa[s] = __builtin_amdgcn_mfma_f32_16x16x32_fp8_fp8(klo, qf0, sa[s], 0, 0, 0);
          sa[s] = __builtin_amdgcn_mfma_f32_16x16x32_fp8_fp8(khi, qf1, sa[s], 0, 0, 0);
        }
      }
      __builtin_amdgcn_s_setprio(0);
      // ---- counted wait + barrier (no drain in steady state)
      if (ch == 1) {
        if (kt < 15) WAITV(2); else WAITV(1);
      } else if (ch >= 4) {
        if (kt < 15) WAITV(1); else WAITV(0);
      } else {
        WAITV(1);
      }
      __builtin_amdgcn_s_barrier();
    }

    // ---- softmax: lane holds rows k = 16s+4g+r for column q = l15
    float fv[16];
    float pmax = -1e30f;
#pragma unroll
    for (int s = 0; s < 4; ++s) {
      float4 cbv = *(const float4*)(cbp + kt * 64 + s * 16 + g * 4);
      fv[s * 4 + 0] = fmaf(sa[s][0], SINV, cbv.x);
      fv[s * 4 + 1] = fmaf(sa[s][1], SINV, cbv.y);
      fv[s * 4 + 2] = fmaf(sa[s][2], SINV, cbv.z);
      fv[s * 4 + 3] = fmaf(sa[s][3], SINV, cbv.w);
#pragma unroll
      for (int r = 0; r < 4; ++r) pmax = fmaxf(pmax, fv[s * 4 + r]);
    }
    pmax = fmaxf(pmax, __shfl_xor(pmax, 16));
    pmax = fmaxf(pmax, __shfl_xor(pmax, 32));
    if (__ballot(pmax > m_run)) {
      float mnew = fmaxf(m_run, pmax);
      float alpha = EXP2F(m_run - mnew);
      lpart *= alpha;
#pragma unroll
      for (int vf = 0; vf < 4; ++vf) oacc[vf] *= alpha;
      m_run = mnew;
    }
    float rs = 0.f;
#pragma unroll
    for (int r = 0; r < 16; ++r) {
      fv[r] = EXP2F(fv[r] - m_run);
      rs += fv[r];
    }
    rs += __shfl_xor(rs, 16);
    rs += __shfl_xor(rs, 32);
    lpart += rs;

    // ---- P pack -> per-wave LDS (b64 writes, 16B-slot swz)
#pragma unroll
    for (int s = 0; s < 4; ++s) {
      unsigned w01, w23;
      asm("v_cvt_pk_bf16_f32 %0, %1, %2" : "=v"(w01) : "v"(fv[s * 4]), "v"(fv[s * 4 + 1]));
      asm("v_cvt_pk_bf16_f32 %0, %1, %2" : "=v"(w23) : "v"(fv[s * 4 + 2]), "v"(fv[s * 4 + 3]));
      int ts = (2 * s + (g >> 1)) ^ (l15 & 7);
      uint2 uu; uu.x = w01; uu.y = w23;
      *(uint2*)((char*)Pb[w] + l15 * 128 + ts * 16 + (g & 1) * 8) = uu;
    }

    // ---- PV: A = V (16d x 32k) from LDS, B = P from LDS (V of kt: Vb[kt&1])
#pragma unroll
    for (int kwin = 0; kwin < 2; ++kwin) {
      int tr = (4 * kwin + g) ^ (l15 & 7);
      bf16x8 pf = *(const bf16x8*)((const char*)Pb[w] + l15 * 128 + tr * 16);
#pragma unroll
      for (int vf = 0; vf < 4; ++vf) {
        int d = vf * 16 + l15;
        bf16x8 vfrag = *(const bf16x8*)((const char*)Vb[kt & 1] + kwin * 4096 + d * 64 +
                                        ((g ^ (d & 3)) * 16));
        oacc[vf] = __builtin_amdgcn_mfma_f32_16x16x32_bf16(vfrag, pf, oacc[vf], 0, 0, 0);
      }
    }
  }

  // ---- epilogue: lane (q=l15) holds d = vf*16+4g+r; divide by l, store u64
  float rdiv = 1.f / lpart;
  size_t nrow = ((size_t)b * 1024 + qt * 128 + w * 16 + l15) * 768;
#pragma unroll
  for (int vf = 0; vf < 4; ++vf) {
    u64 pk = (u64)f2bf(oacc[vf][0] * rdiv) |
             ((u64)f2bf(oacc[vf][1] * rdiv) << 16) |
             ((u64)f2bf(oacc[vf][2] * rdiv) << 32) |
             ((u64)f2bf(oacc[vf][3] * rdiv) << 48);
    *(u64*)&OH[nrow + h * 64 + vf * 16 + 4 * g] = pk;
  }
}

static inline int cvtblocks(int n4) {
  int nb = (n4 + 255) / 256;
  return nb > 2048 ? 2048 : nb;
}

extern "C" void kernel_launch(void* const* d_in, const int* in_sizes, int n_in,
                              void* d_out, int out_size, void* d_ws, size_t ws_size,
                              hipStream_t stream) {
  (void)in_sizes; (void)n_in; (void)out_size; (void)ws_size;
  const float* x = (const float*)d_in[0];
  const float* Wq = (const float*)d_in[1];
  const float* Wk = (const float*)d_in[2];
  const float* Wv = (const float*)d_in[3];
  const float* bv = (const float*)d_in[4];
  const float* Wmix = (const float*)d_in[5];
  const float* Wcb = (const float*)d_in[6];
  const float* Wproj = (const float*)d_in[7];
  const float* bproj = (const float*)d_in[8];
  float* out = (float*)d_out;

  char* ws = (char*)d_ws;
  u16* xbf = (u16*)(ws);                 // 12582912 B
  u16* Wqk = (u16*)(ws + 12582912);      // 2359296 B
  u16* Wvcb = (u16*)(ws + 14942208);     // 1376256 B
  u16* Wpj = (u16*)(ws + 16318464);      // 1179648 B
  u16* Qb = (u16*)(ws + 17498112);       // 12582912 B
  u8* Kf8 = (u8*)(ws + 30081024);        // 6291456 B
  u16* vT = (u16*)(ws + 36372480);       // 12582912 B
  float* cbb = (float*)(ws + 48955392);  // 393216 B
  u16* OH = (u16*)(ws + 49348608);       // 12582912 B (end 61931520)

  cvt_f32_bf16<<<cvtblocks(1572864), 256, 0, stream>>>((const float4*)x, (uint2*)xbf, 1572864);
  cvt_f32_bf16<<<cvtblocks(147456), 256, 0, stream>>>((const float4*)Wq, (uint2*)Wqk, 147456);
  cvt_f32_bf16<<<cvtblocks(147456), 256, 0, stream>>>((const float4*)Wk, (uint2*)(Wqk + 589824), 147456);
  cvt_f32_bf16<<<cvtblocks(147456), 256, 0, stream>>>((const float4*)Wv, (uint2*)Wvcb, 147456);
  cvt_f32_bf16<<<cvtblocks(2304), 256, 0, stream>>>((const float4*)Wcb, (uint2*)(Wvcb + 589824), 2304);
  cvt_f32_bf16<<<cvtblocks(147456), 256, 0, stream>>>((const float4*)Wproj, (uint2*)Wpj, 147456);

  gemm_bt<0><<<dim3(12, 64), 256, 0, stream>>>(xbf, Wqk, Qb, Kf8, nullptr, 0);
  gemm_bt<1><<<dim3(64, 7), 256, 0, stream>>>(Wvcb, xbf, vT, cbb, bv, 0);
  attn8<<<dim3(768), 512, 0, stream>>>(Qb, Kf8, vT, cbb, Wmix, OH);
  gemm_bt<2><<<dim3(6, 64), 256, 0, stream>>>(OH, Wpj, out, nullptr, bproj, 768);
}